// Round 1
// baseline (3455.807 us; speedup 1.0000x reference)
//
#include <hip/hip_runtime.h>
#include <hip/hip_bf16.h>
#include <math.h>

// Problem constants (from reference)
#define BB    2
#define TT    1024
#define HID   1024
#define NQ    8
#define NK    4
#define DK    128
#define DV    128
#define TOT   3088      // KDIM+KKDIM+KVDIM+VDIM+NQ+NQ = 1024+512+512+1024+8+8
#define CONVD 2048
#define KSZ   4
#define BT    (BB*TT)   // 2048

__device__ __forceinline__ float siluf(float x)     { return x / (1.f + expf(-x)); }
__device__ __forceinline__ float sigmoidf_(float x) { return 1.f / (1.f + expf(-x)); }
__device__ __forceinline__ float softplusf_(float x){ return x > 15.f ? x : log1pf(expf(x)); }

// ---------------- generic tiled fp32 GEMM: C[M,N] = A[M,K] @ B[K,N], row-major ----------------
// BM=BN=64, BK=16, 256 threads, 4x4 per thread. N may be non-multiple of 64 (guarded).
__global__ __launch_bounds__(256) void gemm_f32(const float* __restrict__ A,
                                                const float* __restrict__ Bm,
                                                float* __restrict__ C,
                                                int M, int N, int K) {
    const int BM = 64, BN = 64, BK = 16;
    __shared__ float As[16][65];   // +1 pad: avoid 16-way bank conflict on store
    __shared__ float Bs[16][64];
    int row0 = blockIdx.y * BM, col0 = blockIdx.x * BN;
    int tid = threadIdx.x;
    int tx = tid & 15, ty = tid >> 4;
    float acc[4][4] = {};
    for (int k0 = 0; k0 < K; k0 += BK) {
        // A tile: 64x16, 4 elems/thread. consecutive tid -> consecutive k (coalesced 16-float runs)
        #pragma unroll
        for (int i = 0; i < 4; i++) {
            int idx = tid + i * 256;
            int m = idx >> 4, kk = idx & 15;
            int gr = row0 + m;
            As[kk][m] = (gr < M) ? A[(size_t)gr * K + k0 + kk] : 0.f;
        }
        // B tile: 16x64, consecutive tid -> consecutive n (coalesced)
        #pragma unroll
        for (int i = 0; i < 4; i++) {
            int idx = tid + i * 256;
            int kk = idx >> 6, n = idx & 63;
            int gc = col0 + n;
            Bs[kk][n] = (gc < N) ? Bm[(size_t)(k0 + kk) * N + gc] : 0.f;
        }
        __syncthreads();
        #pragma unroll
        for (int kk = 0; kk < BK; kk++) {
            float a[4], b[4];
            #pragma unroll
            for (int i = 0; i < 4; i++) a[i] = As[kk][ty * 4 + i];
            #pragma unroll
            for (int j = 0; j < 4; j++) b[j] = Bs[kk][tx * 4 + j];
            #pragma unroll
            for (int i = 0; i < 4; i++)
                #pragma unroll
                for (int j = 0; j < 4; j++)
                    acc[i][j] += a[i] * b[j];
        }
        __syncthreads();
    }
    #pragma unroll
    for (int i = 0; i < 4; i++) {
        int gr = row0 + ty * 4 + i;
        if (gr >= M) continue;
        #pragma unroll
        for (int j = 0; j < 4; j++) {
            int gc = col0 + tx * 4 + j;
            if (gc < N) C[(size_t)gr * N + gc] = acc[i][j];
        }
    }
}

// ---------------- conv + silu + split + l2norm + beta/g ----------------
// one block per (b,t), 256 threads, 8 consecutive channels per thread (stays within one head)
__global__ __launch_bounds__(256) void conv_split_kernel(const float* __restrict__ mixed,
                                                         const float* __restrict__ conv_w,
                                                         const float* __restrict__ A_log,
                                                         const float* __restrict__ dt_bias,
                                                         float* __restrict__ qn,
                                                         float* __restrict__ kn,
                                                         float* __restrict__ vn,
                                                         float* __restrict__ beta,
                                                         float* __restrict__ g) {
    int bt = blockIdx.x;
    int t = bt & (TT - 1);
    int tid = threadIdx.x;
    int c0 = tid * 8;

    float val[8];
    #pragma unroll
    for (int i = 0; i < 8; i++) val[i] = 0.f;
    #pragma unroll
    for (int j = 0; j < KSZ; j++) {
        int tt = t - (KSZ - 1) + j;
        if (tt >= 0) {
            const float* src = mixed + (size_t)(bt - (KSZ - 1) + j) * TOT + c0;
            #pragma unroll
            for (int i = 0; i < 8; i++) val[i] += src[i] * conv_w[(c0 + i) * KSZ + j];
        }
    }
    #pragma unroll
    for (int i = 0; i < 8; i++) val[i] = siluf(val[i]);

    // sum of squares across the 16-thread group that owns one 128-wide head
    float ss = 0.f;
    #pragma unroll
    for (int i = 0; i < 8; i++) ss += val[i] * val[i];
    #pragma unroll
    for (int m = 1; m < 16; m <<= 1) ss += __shfl_xor(ss, m, 64);
    float rs = rsqrtf(ss + 1e-6f);

    if (tid < 128) {                         // q -> l2norm * DK^-0.5
        float sc = rs * 0.08838834764831845f;
        #pragma unroll
        for (int i = 0; i < 8; i++) qn[(size_t)bt * 1024 + c0 + i] = val[i] * sc;
    } else if (tid < 192) {                  // k -> l2norm
        #pragma unroll
        for (int i = 0; i < 8; i++) kn[(size_t)bt * 512 + (c0 - 1024) + i] = val[i] * rs;
    } else {                                 // v -> silu only
        #pragma unroll
        for (int i = 0; i < 8; i++) vn[(size_t)bt * 512 + (c0 - 1536) + i] = val[i];
    }
    if (tid < 8) {
        beta[bt * 8 + tid] = sigmoidf_(mixed[(size_t)bt * TOT + 3072 + tid]);
    } else if (tid < 16) {
        int h = tid - 8;
        g[bt * 8 + h] = -expf(A_log[h]) * softplusf_(mixed[(size_t)bt * TOT + 3080 + h] + dt_bias[h]);
    }
}

// ---------------- sequential gated delta-rule scan ----------------
// one block per (b,h): 16 blocks, 128 threads. Lane v owns column v of S[128][128].
__global__ __launch_bounds__(128) void scan_kernel(const float* __restrict__ qn,
                                                   const float* __restrict__ kn,
                                                   const float* __restrict__ vn,
                                                   const float* __restrict__ beta,
                                                   const float* __restrict__ g,
                                                   float* __restrict__ o) {
    int bh = blockIdx.x;
    int b = bh >> 3, h = bh & 7, hk = h >> 1;
    int v = threadIdx.x;
    __shared__ float ks[128], qs[128];
    float S[128];
    #pragma unroll
    for (int i = 0; i < 128; i++) S[i] = 0.f;

    for (int t = 0; t < TT; t++) {
        int bt = b * TT + t;
        __syncthreads();
        ks[v] = kn[(size_t)bt * 512 + hk * 128 + v];
        qs[v] = qn[(size_t)bt * 1024 + h * 128 + v];
        __syncthreads();
        float gamma = expf(g[bt * 8 + h]);
        float bb = beta[bt * 8 + h];
        float vt = vn[(size_t)bt * 512 + hk * 128 + v];

        float a0 = 0.f, a1 = 0.f, a2 = 0.f, a3 = 0.f;
        #pragma unroll
        for (int i = 0; i < 128; i += 4) {
            a0 += ks[i] * S[i];
            a1 += ks[i + 1] * S[i + 1];
            a2 += ks[i + 2] * S[i + 2];
            a3 += ks[i + 3] * S[i + 3];
        }
        float kS = (a0 + a1) + (a2 + a3);
        float u = bb * (vt - gamma * kS);

        float o0 = 0.f, o1 = 0.f, o2 = 0.f, o3 = 0.f;
        #pragma unroll
        for (int i = 0; i < 128; i += 4) {
            S[i]     = gamma * S[i]     + ks[i]     * u; o0 += qs[i]     * S[i];
            S[i + 1] = gamma * S[i + 1] + ks[i + 1] * u; o1 += qs[i + 1] * S[i + 1];
            S[i + 2] = gamma * S[i + 2] + ks[i + 2] * u; o2 += qs[i + 2] * S[i + 2];
            S[i + 3] = gamma * S[i + 3] + ks[i + 3] * u; o3 += qs[i + 3] * S[i + 3];
        }
        o[(size_t)bt * 1024 + h * 128 + v] = (o0 + o1) + (o2 + o3);
    }
}

// ---------------- gated RMS norm + silu(z) gate ----------------
// one block (1 wave) per (b,t,h)
__global__ __launch_bounds__(64) void norm_gate_kernel(const float* __restrict__ o_scan,
                                                       const float* __restrict__ mixed,
                                                       const float* __restrict__ norm_w,
                                                       float* __restrict__ gin) {
    int bth = blockIdx.x;
    int bt = bth >> 3, h = bth & 7;
    int lane = threadIdx.x;
    size_t base = (size_t)bt * 1024 + h * 128;
    float o0 = o_scan[base + lane];
    float o1 = o_scan[base + lane + 64];
    float ss = o0 * o0 + o1 * o1;
    #pragma unroll
    for (int m = 1; m < 64; m <<= 1) ss += __shfl_xor(ss, m, 64);
    float r = rsqrtf(ss * (1.f / 128.f) + 1e-5f);
    size_t zbase = (size_t)bt * TOT + 2048 + h * 128;
    float z0 = mixed[zbase + lane];
    float z1 = mixed[zbase + lane + 64];
    gin[base + lane]      = o0 * r * norm_w[lane]      * siluf(z0);
    gin[base + lane + 64] = o1 * r * norm_w[lane + 64] * siluf(z1);
}

extern "C" void kernel_launch(void* const* d_in, const int* in_sizes, int n_in,
                              void* d_out, int out_size, void* d_ws, size_t ws_size,
                              hipStream_t stream) {
    const float* x       = (const float*)d_in[0];
    const float* w_in    = (const float*)d_in[1];
    const float* conv_w  = (const float*)d_in[2];
    const float* A_log   = (const float*)d_in[3];
    const float* dt_bias = (const float*)d_in[4];
    const float* norm_w  = (const float*)d_in[5];
    const float* w_out   = (const float*)d_in[6];
    float* out = (float*)d_out;

    float* ws    = (float*)d_ws;
    float* mixed = ws;                         // 2048*3088 = 6,324,224
    float* qn    = mixed + (size_t)BT * TOT;   // 2048*1024
    float* kn    = qn + (size_t)BT * 1024;     // 2048*512
    float* vn    = kn + (size_t)BT * 512;      // 2048*512
    float* beta  = vn + (size_t)BT * 512;      // 16384
    float* gdec  = beta + BT * 8;              // 16384
    float* oscan = gdec + BT * 8;              // 2048*1024
    float* gin   = qn;                         // alias: qn dead after scan

    // 1) mixed = x @ w_in   [2048,1024]x[1024,3088]
    dim3 g1((TOT + 63) / 64, BT / 64);
    gemm_f32<<<g1, 256, 0, stream>>>(x, w_in, mixed, BT, TOT, HID);

    // 2) conv + silu + split + l2norm + beta/g
    conv_split_kernel<<<BT, 256, 0, stream>>>(mixed, conv_w, A_log, dt_bias, qn, kn, vn, beta, gdec);

    // 3) sequential scan
    scan_kernel<<<BB * NQ, 128, 0, stream>>>(qn, kn, vn, beta, gdec, oscan);

    // 4) gated RMS norm + silu(z)
    norm_gate_kernel<<<BT * NQ, 64, 0, stream>>>(oscan, mixed, norm_w, gin);

    // 5) out = gin @ w_out   [2048,1024]x[1024,1024]
    dim3 g2(HID / 64, BT / 64);
    gemm_f32<<<g2, 256, 0, stream>>>(gin, w_out, out, BT, HID, HID);
}

// Round 2
// 798.201 us; speedup vs baseline: 4.3295x; 4.3295x over previous
//
#include <hip/hip_runtime.h>
#include <hip/hip_bf16.h>
#include <math.h>

// Problem constants (from reference)
#define BB    2
#define TT    1024
#define HID   1024
#define NQ    8
#define NK    4
#define DK    128
#define DV    128
#define TOT   3088      // 1024+512+512+1024+8+8
#define CONVD 2048
#define KSZ   4
#define BT    (BB*TT)   // 2048
#define CHUNK 64
#define NCHUNK (TT/CHUNK)   // 16
#define NBH   (BB*NQ)       // 16

__device__ __forceinline__ float siluf(float x)     { return x / (1.f + expf(-x)); }
__device__ __forceinline__ float sigmoidf_(float x) { return 1.f / (1.f + expf(-x)); }
__device__ __forceinline__ float softplusf_(float x){ return x > 15.f ? x : log1pf(expf(x)); }

// ---------------- generic tiled fp32 GEMM: C[M,N] = A[M,K] @ B[K,N], row-major ----------------
__global__ __launch_bounds__(256) void gemm_f32(const float* __restrict__ A,
                                                const float* __restrict__ Bm,
                                                float* __restrict__ C,
                                                int M, int N, int K) {
    const int BK = 16;
    __shared__ float As[16][65];
    __shared__ float Bs[16][64];
    int row0 = blockIdx.y * 64, col0 = blockIdx.x * 64;
    int tid = threadIdx.x;
    int tx = tid & 15, ty = tid >> 4;
    float acc[4][4] = {};
    for (int k0 = 0; k0 < K; k0 += BK) {
        #pragma unroll
        for (int i = 0; i < 4; i++) {
            int idx = tid + i * 256;
            int m = idx >> 4, kk = idx & 15;
            int gr = row0 + m;
            As[kk][m] = (gr < M) ? A[(size_t)gr * K + k0 + kk] : 0.f;
        }
        #pragma unroll
        for (int i = 0; i < 4; i++) {
            int idx = tid + i * 256;
            int kk = idx >> 6, n = idx & 63;
            int gc = col0 + n;
            Bs[kk][n] = (gc < N) ? Bm[(size_t)(k0 + kk) * N + gc] : 0.f;
        }
        __syncthreads();
        #pragma unroll
        for (int kk = 0; kk < BK; kk++) {
            float a[4], b[4];
            #pragma unroll
            for (int i = 0; i < 4; i++) a[i] = As[kk][ty * 4 + i];
            #pragma unroll
            for (int j = 0; j < 4; j++) b[j] = Bs[kk][tx * 4 + j];
            #pragma unroll
            for (int i = 0; i < 4; i++)
                #pragma unroll
                for (int j = 0; j < 4; j++)
                    acc[i][j] += a[i] * b[j];
        }
        __syncthreads();
    }
    #pragma unroll
    for (int i = 0; i < 4; i++) {
        int gr = row0 + ty * 4 + i;
        if (gr >= M) continue;
        #pragma unroll
        for (int j = 0; j < 4; j++) {
            int gc = col0 + tx * 4 + j;
            if (gc < N) C[(size_t)gr * N + gc] = acc[i][j];
        }
    }
}

// ---------------- conv + silu + split + l2norm + beta/g ----------------
__global__ __launch_bounds__(256) void conv_split_kernel(const float* __restrict__ mixed,
                                                         const float* __restrict__ conv_w,
                                                         const float* __restrict__ A_log,
                                                         const float* __restrict__ dt_bias,
                                                         float* __restrict__ qn,
                                                         float* __restrict__ kn,
                                                         float* __restrict__ vn,
                                                         float* __restrict__ beta,
                                                         float* __restrict__ g) {
    int bt = blockIdx.x;
    int t = bt & (TT - 1);
    int tid = threadIdx.x;
    int c0 = tid * 8;

    float val[8];
    #pragma unroll
    for (int i = 0; i < 8; i++) val[i] = 0.f;
    #pragma unroll
    for (int j = 0; j < KSZ; j++) {
        int tt = t - (KSZ - 1) + j;
        if (tt >= 0) {
            const float* src = mixed + (size_t)(bt - (KSZ - 1) + j) * TOT + c0;
            #pragma unroll
            for (int i = 0; i < 8; i++) val[i] += src[i] * conv_w[(c0 + i) * KSZ + j];
        }
    }
    #pragma unroll
    for (int i = 0; i < 8; i++) val[i] = siluf(val[i]);

    float ss = 0.f;
    #pragma unroll
    for (int i = 0; i < 8; i++) ss += val[i] * val[i];
    #pragma unroll
    for (int m = 1; m < 16; m <<= 1) ss += __shfl_xor(ss, m, 64);
    float rs = rsqrtf(ss + 1e-6f);

    if (tid < 128) {
        float sc = rs * 0.08838834764831845f;
        #pragma unroll
        for (int i = 0; i < 8; i++) qn[(size_t)bt * 1024 + c0 + i] = val[i] * sc;
    } else if (tid < 192) {
        #pragma unroll
        for (int i = 0; i < 8; i++) kn[(size_t)bt * 512 + (c0 - 1024) + i] = val[i] * rs;
    } else {
        #pragma unroll
        for (int i = 0; i < 8; i++) vn[(size_t)bt * 512 + (c0 - 1536) + i] = val[i];
    }
    if (tid < 8) {
        beta[bt * 8 + tid] = sigmoidf_(mixed[(size_t)bt * TOT + 3072 + tid]);
    } else if (tid < 16) {
        int h = tid - 8;
        g[bt * 8 + h] = -expf(A_log[h]) * softplusf_(mixed[(size_t)bt * TOT + 3080 + h] + dt_bias[h]);
    }
}

// ---------------- Phase A: per-chunk UT transform ----------------
// block = chunk (bh*16+c). Computes W = T^-1 diag(beta) V, Z = T^-1 diag(beta*Gamma) K.
// T = I + strictly_lower(beta_t * exp(B_t - B_s) * k_t.k_s).
__global__ __launch_bounds__(256) void phaseA_kernel(const float* __restrict__ kn,
                                                     const float* __restrict__ vn,
                                                     const float* __restrict__ beta,
                                                     const float* __restrict__ g,
                                                     float* __restrict__ W,
                                                     float* __restrict__ Z,
                                                     float* __restrict__ Bvec) {
    int chunk = blockIdx.x;
    int bh = chunk >> 4, c = chunk & 15;
    int b = bh >> 3, h = bh & 7, hk = h >> 1;
    int bt0 = b * TT + c * CHUNK;
    __shared__ float kc[64][129];
    __shared__ float M[64][65];
    __shared__ float X[64][256];
    __shared__ float Bv[64], Bev[64], bev[64];
    int tid = threadIdx.x;

    if (tid < 64) {
        float v = g[(size_t)(bt0 + tid) * 8 + h];
        #pragma unroll
        for (int off = 1; off < 64; off <<= 1) {
            float n = __shfl_up(v, off, 64);
            if (tid >= off) v += n;
        }
        Bv[tid] = v;
        Bev[tid] = expf(v);
        bev[tid] = beta[(size_t)(bt0 + tid) * 8 + h];
        Bvec[chunk * 64 + tid] = v;
    }
    for (int i = tid; i < 8192; i += 256) {
        int t = i >> 7, r = i & 127;
        kc[t][r] = kn[(size_t)(bt0 + t) * 512 + hk * 128 + r];
    }
    __syncthreads();

    // M[t][s] for s<t (zeros elsewhere)
    {
        int t = tid & 63, sg = tid >> 6;
        for (int ss = 0; ss < 16; ss++) {
            int s = sg * 16 + ss;
            float acc = 0.f;
            if (s < t) {
                for (int i = 0; i < 128; i++) acc += kc[t][i] * kc[s][i];
                acc *= bev[t] * expf(Bv[t] - Bv[s]);
            }
            M[t][s] = acc;
        }
    }
    // RHS: X[t][0:128] = beta_t*v_t ; X[t][128:256] = beta_t*Gamma_t*k_t
    for (int i = tid; i < 8192; i += 256) {
        int t = i >> 7, r = i & 127;
        X[t][r]       = bev[t] * vn[(size_t)(bt0 + t) * 512 + hk * 128 + r];
        X[t][128 + r] = bev[t] * Bev[t] * kc[t][r];
    }
    __syncthreads();
    // forward substitution: X[t] -= sum_{s<t} M[t][s] * X[s]
    for (int t = 1; t < 64; t++) {
        float acc = 0.f;
        for (int s = 0; s < t; s++) acc += M[t][s] * X[s][tid];
        X[t][tid] -= acc;
        __syncthreads();
    }
    float* Wc = W + (size_t)chunk * 8192;
    float* Zc = Z + (size_t)chunk * 8192;
    for (int i = tid; i < 8192; i += 256) {
        int t = i >> 7, r = i & 127;
        Wc[i] = X[t][r];
        Zc[i] = X[t][128 + r];
    }
}

// ---------------- Phase B: sequential over chunks, parallel over (bh, 32-col groups) ----------------
// U = W - Z S_c (written over W);  S_{c+1} = exp(B_C) S_c + K_hat^T U;  stores S_c per chunk.
__global__ __launch_bounds__(256) void phaseB_kernel(const float* __restrict__ kn,
                                                     float* __restrict__ WU,
                                                     const float* __restrict__ Z,
                                                     const float* __restrict__ Bvec,
                                                     float* __restrict__ Sall) {
    int bh = blockIdx.x >> 2, cg = blockIdx.x & 3;
    int b = bh >> 3, h = bh & 7, hk = h >> 1;
    __shared__ float Zt[128][65];   // Z transposed: Zt[k][t]
    __shared__ float Kl[64][129];   // K_hat[s][r]
    __shared__ float Sc[128][36];   // state slice, 32 cols
    __shared__ float Ul[64][36];    // W slice -> U slice
    __shared__ float Bv[64];
    int tid = threadIdx.x;

    for (int i = tid; i < 128 * 32; i += 256) Sc[i >> 5][i & 31] = 0.f;

    for (int c = 0; c < NCHUNK; c++) {
        int chunk = bh * 16 + c;
        int bt0 = b * TT + c * CHUNK;
        __syncthreads();                                    // (1)
        // store S_c slice
        float* Sg = Sall + (size_t)chunk * 16384 + cg * 32;
        for (int i = tid; i < 128 * 32; i += 256) {
            int r = i >> 5, j = i & 31;
            Sg[(size_t)r * 128 + j] = Sc[r][j];
        }
        if (tid < 64) Bv[tid] = Bvec[chunk * 64 + tid];
        const float* Zc = Z + (size_t)chunk * 8192;
        for (int i = tid; i < 8192; i += 256) Zt[i & 127][i >> 7] = Zc[i];
        __syncthreads();                                    // (2) Bv ready
        float BC = Bv[63];
        float gC = expf(BC);
        for (int i = tid; i < 8192; i += 256) {
            int s = i >> 7, r = i & 127;
            Kl[s][r] = kn[(size_t)(bt0 + s) * 512 + hk * 128 + r] * expf(BC - Bv[s]);
        }
        float* Wc = WU + (size_t)chunk * 8192;
        for (int i = tid; i < 64 * 32; i += 256) {
            int t = i >> 5, j = i & 31;
            Ul[t][j] = Wc[(size_t)t * 128 + cg * 32 + j];
        }
        __syncthreads();                                    // (3)
        // U = W - Z S
        {
            int tr = tid & 63, tc = tid >> 6;
            int j0 = tc * 8;
            float acc[8] = {};
            for (int kk = 0; kk < 128; kk++) {
                float zv = Zt[kk][tr];
                float4 s0 = *(const float4*)&Sc[kk][j0];
                float4 s1 = *(const float4*)&Sc[kk][j0 + 4];
                acc[0] += zv * s0.x; acc[1] += zv * s0.y; acc[2] += zv * s0.z; acc[3] += zv * s0.w;
                acc[4] += zv * s1.x; acc[5] += zv * s1.y; acc[6] += zv * s1.z; acc[7] += zv * s1.w;
            }
            #pragma unroll
            for (int j = 0; j < 8; j++) Ul[tr][j0 + j] -= acc[j];
        }
        __syncthreads();                                    // (4) U final
        for (int i = tid; i < 64 * 32; i += 256) {
            int t = i >> 5, j = i & 31;
            Wc[(size_t)t * 128 + cg * 32 + j] = Ul[t][j];
        }
        // S' = gC*S + K_hat^T U
        {
            int r = tid & 127, th = tid >> 7;
            int j1 = th * 16;
            float sacc[16];
            #pragma unroll
            for (int j = 0; j < 16; j++) sacc[j] = gC * Sc[r][j1 + j];
            for (int s = 0; s < 64; s++) {
                float kv = Kl[s][r];
                #pragma unroll
                for (int jq = 0; jq < 4; jq++) {
                    float4 uv = *(const float4*)&Ul[s][j1 + jq * 4];
                    sacc[jq * 4 + 0] += kv * uv.x; sacc[jq * 4 + 1] += kv * uv.y;
                    sacc[jq * 4 + 2] += kv * uv.z; sacc[jq * 4 + 3] += kv * uv.w;
                }
            }
            #pragma unroll
            for (int j = 0; j < 16; j++) Sc[r][j1 + j] = sacc[j];
        }
    }
}

// ---------------- Phase C: per-chunk outputs ----------------
// O[t] = Gamma_t * q_t S_c + sum_{s<=t} exp(B_t-B_s)(q_t.k_s) U[s]
__global__ __launch_bounds__(256) void phaseC_kernel(const float* __restrict__ qn,
                                                     const float* __restrict__ kn,
                                                     const float* __restrict__ U,
                                                     const float* __restrict__ Sall,
                                                     const float* __restrict__ Bvec,
                                                     float* __restrict__ o) {
    int chunk = blockIdx.x;
    int bh = chunk >> 4, c = chunk & 15;
    int b = bh >> 3, h = bh & 7, hk = h >> 1;
    int bt0 = b * TT + c * CHUNK;
    __shared__ float qc[64][129];
    __shared__ float kc[64][129];   // reused as U buffer
    __shared__ float P[64][65];
    __shared__ float Bv[64];
    int tid = threadIdx.x;

    if (tid < 64) Bv[tid] = Bvec[chunk * 64 + tid];
    for (int i = tid; i < 8192; i += 256) {
        int t = i >> 7, r = i & 127;
        qc[t][r] = qn[(size_t)(bt0 + t) * 1024 + h * 128 + r];
        kc[t][r] = kn[(size_t)(bt0 + t) * 512 + hk * 128 + r];
    }
    __syncthreads();
    // P[t][s] = exp(B_t-B_s) * q_t.k_s for s<=t (zeros elsewhere)
    {
        int t = tid & 63, sg = tid >> 6;
        for (int ss = 0; ss < 16; ss++) {
            int s = sg * 16 + ss;
            float acc = 0.f;
            if (s <= t) {
                for (int i = 0; i < 128; i++) acc += qc[t][i] * kc[s][i];
                acc *= expf(Bv[t] - Bv[s]);
            }
            P[t][s] = acc;
        }
    }
    __syncthreads();
    // overwrite kc with U
    const float* Uc = U + (size_t)chunk * 8192;
    for (int i = tid; i < 8192; i += 256) {
        int t = i >> 7, r = i & 127;
        kc[t][r] = Uc[i];
    }
    __syncthreads();
    {
        int j = tid & 127, tq = tid >> 7;
        const float* Sg = Sall + (size_t)chunk * 16384;
        float acc[32] = {};
        for (int r = 0; r < 128; r++) {
            float sv = Sg[(size_t)r * 128 + j];
            #pragma unroll
            for (int u2 = 0; u2 < 32; u2++) acc[u2] += qc[tq * 32 + u2][r] * sv;
        }
        #pragma unroll
        for (int u2 = 0; u2 < 32; u2++) acc[u2] *= expf(Bv[tq * 32 + u2]);
        for (int s = 0; s < 64; s++) {
            float uv = kc[s][j];
            #pragma unroll
            for (int u2 = 0; u2 < 32; u2++) acc[u2] += P[tq * 32 + u2][s] * uv;
        }
        #pragma unroll
        for (int u2 = 0; u2 < 32; u2++) {
            int t = tq * 32 + u2;
            o[(size_t)(bt0 + t) * 1024 + h * 128 + j] = acc[u2];
        }
    }
}

// ---------------- gated RMS norm + silu(z) gate ----------------
__global__ __launch_bounds__(64) void norm_gate_kernel(const float* __restrict__ o_scan,
                                                       const float* __restrict__ mixed,
                                                       const float* __restrict__ norm_w,
                                                       float* __restrict__ gin) {
    int bth = blockIdx.x;
    int bt = bth >> 3, h = bth & 7;
    int lane = threadIdx.x;
    size_t base = (size_t)bt * 1024 + h * 128;
    float o0 = o_scan[base + lane];
    float o1 = o_scan[base + lane + 64];
    float ss = o0 * o0 + o1 * o1;
    #pragma unroll
    for (int m = 1; m < 64; m <<= 1) ss += __shfl_xor(ss, m, 64);
    float r = rsqrtf(ss * (1.f / 128.f) + 1e-5f);
    size_t zbase = (size_t)bt * TOT + 2048 + h * 128;
    float z0 = mixed[zbase + lane];
    float z1 = mixed[zbase + lane + 64];
    gin[base + lane]      = o0 * r * norm_w[lane]      * siluf(z0);
    gin[base + lane + 64] = o1 * r * norm_w[lane + 64] * siluf(z1);
}

extern "C" void kernel_launch(void* const* d_in, const int* in_sizes, int n_in,
                              void* d_out, int out_size, void* d_ws, size_t ws_size,
                              hipStream_t stream) {
    const float* x       = (const float*)d_in[0];
    const float* w_in    = (const float*)d_in[1];
    const float* conv_w  = (const float*)d_in[2];
    const float* A_log   = (const float*)d_in[3];
    const float* dt_bias = (const float*)d_in[4];
    const float* norm_w  = (const float*)d_in[5];
    const float* w_out   = (const float*)d_in[6];
    float* out = (float*)d_out;

    float* ws    = (float*)d_ws;
    float* mixed = ws;                           // 6,324,224
    float* qn    = mixed + (size_t)BT * TOT;     // 2,097,152
    float* kn    = qn + (size_t)BT * 1024;       // 1,048,576
    float* vn    = kn + (size_t)BT * 512;        // 1,048,576
    float* beta  = vn + (size_t)BT * 512;        // 16,384
    float* gdec  = beta + BT * 8;                // 16,384
    float* Wu    = gdec + BT * 8;                // 2,097,152 (W -> U -> gin)
    float* Zz    = Wu + (size_t)BT * 1024;       // 2,097,152 (Z -> oscan)
    float* Bvec  = Zz + (size_t)BT * 1024;       // 16,384
    float* Sall  = Bvec + NBH * NCHUNK * 64;     // 4,194,304
    float* oscan = Zz;                           // alias: Z dead after phase B
    float* gin   = Wu;                           // alias: U dead after phase C

    // 1) mixed = x @ w_in
    dim3 g1((TOT + 63) / 64, BT / 64);
    gemm_f32<<<g1, 256, 0, stream>>>(x, w_in, mixed, BT, TOT, HID);

    // 2) conv + silu + split + l2norm + beta/g
    conv_split_kernel<<<BT, 256, 0, stream>>>(mixed, conv_w, A_log, dt_bias, qn, kn, vn, beta, gdec);

    // 3) chunkwise delta-rule scan
    phaseA_kernel<<<NBH * NCHUNK, 256, 0, stream>>>(kn, vn, beta, gdec, Wu, Zz, Bvec);
    phaseB_kernel<<<NBH * 4, 256, 0, stream>>>(kn, Wu, Zz, Bvec, Sall);
    phaseC_kernel<<<NBH * NCHUNK, 256, 0, stream>>>(qn, kn, Wu, Sall, Bvec, oscan);

    // 4) gated RMS norm + silu(z)
    norm_gate_kernel<<<BT * NQ, 64, 0, stream>>>(oscan, mixed, norm_w, gin);

    // 5) out = gin @ w_out
    dim3 g2(HID / 64, BT / 64);
    gemm_f32<<<g2, 256, 0, stream>>>(gin, w_out, out, BT, HID, HID);
}

// Round 3
// 441.419 us; speedup vs baseline: 7.8289x; 1.8083x over previous
//
#include <hip/hip_runtime.h>
#include <hip/hip_bf16.h>
#include <math.h>

// Problem constants (from reference)
#define BB    2
#define TT    1024
#define HID   1024
#define NQ    8
#define NK    4
#define DK    128
#define DV    128
#define TOT   3088      // 1024+512+512+1024+8+8
#define CONVD 2048
#define KSZ   4
#define BT    (BB*TT)   // 2048
#define CHUNK 64
#define NCHUNK (TT/CHUNK)   // 16
#define NBH   (BB*NQ)       // 16
#define NPAD1 3200          // 3088 padded to 25*128

typedef __attribute__((ext_vector_type(8))) short short8v;
typedef __attribute__((ext_vector_type(4))) float f32x4;
typedef unsigned short ushort_t;
typedef unsigned int uint_t;

__device__ __forceinline__ float siluf(float x)     { return x / (1.f + expf(-x)); }
__device__ __forceinline__ float sigmoidf_(float x) { return 1.f / (1.f + expf(-x)); }
__device__ __forceinline__ float softplusf_(float x){ return x > 15.f ? x : log1pf(expf(x)); }

__device__ __forceinline__ ushort_t f2bf(float f) {
    uint_t u = __builtin_bit_cast(uint_t, f);
    u = (u + 0x7fff + ((u >> 16) & 1)) >> 16;
    return (ushort_t)u;
}

// ---------------- elementwise f32 -> bf16 ----------------
__global__ __launch_bounds__(256) void f2bf_kernel(const float* __restrict__ src,
                                                   ushort_t* __restrict__ dst) {
    int i = (blockIdx.x * 256 + threadIdx.x) * 4;
    float4 v = *(const float4*)(src + i);
    ushort4 o;
    o.x = f2bf(v.x); o.y = f2bf(v.y); o.z = f2bf(v.z); o.w = f2bf(v.w);
    *(ushort4*)(dst + i) = o;
}

// ---------------- tiled transpose + convert: dst[n][k] = bf16(src[k][n]) ----------------
// grid: (Npad/32, K/32). Rows n >= N are zero-filled.
__global__ __launch_bounds__(256) void transpose_f2bf(const float* __restrict__ src,
                                                      ushort_t* __restrict__ dst,
                                                      int K, int N) {
    __shared__ float tile[32][33];
    int n0 = blockIdx.x * 32, k0 = blockIdx.y * 32;
    int c = threadIdx.x & 31, rbase = threadIdx.x >> 5;
    #pragma unroll
    for (int i = 0; i < 4; i++) {
        int r = rbase + i * 8;
        int n = n0 + c;
        tile[r][c] = (n < N) ? src[(size_t)(k0 + r) * N + n] : 0.f;
    }
    __syncthreads();
    #pragma unroll
    for (int i = 0; i < 4; i++) {
        int r = rbase + i * 8;
        dst[(size_t)(n0 + r) * K + k0 + c] = f2bf(tile[c][r]);
    }
}

// ---------------- bf16 MFMA GEMM (m97 structure): C[M,N] = A[M,K] @ BT[N,K]^T ----------------
// A: bf16 [M][K] row-major; BT: bf16 [Npad][K] (B transposed); C: fp32, stride ldc, col-guard Nc.
// 128x128 tile, BK=32, 256 threads = 4 waves (2x2 of 64x64), 4x4 16x16x32 frags per wave.
__global__ __launch_bounds__(256) void gemm_bf16(const ushort_t* __restrict__ A,
                                                 const ushort_t* __restrict__ BTm,
                                                 float* __restrict__ C,
                                                 int K, int Nc, int ldc) {
    __shared__ ushort_t As[128 * 32];
    __shared__ ushort_t Bs[128 * 32];
    int tid = threadIdx.x;
    int wave = tid >> 6, lane = tid & 63;
    int wr = wave >> 1, wc = wave & 1;
    int row0 = blockIdx.y * 128, col0 = blockIdx.x * 128;

    f32x4 zero4 = {0.f, 0.f, 0.f, 0.f};
    f32x4 acc[4][4];
    #pragma unroll
    for (int m = 0; m < 4; m++)
        #pragma unroll
        for (int n = 0; n < 4; n++) acc[m][n] = zero4;

    // staging: wave w, pass p fills LDS bytes [(w*2+p)*1024, +1024); lane l -> 16 B at +l*16
    int srow = wave * 32 + (lane >> 2);          // rows 0..127 over (wave,pass,lane/4)
    int koff = (lane & 3) * 8;
    const ushort_t* gA0 = A + (size_t)(row0 + srow) * K + koff;
    const ushort_t* gA1 = A + (size_t)(row0 + srow + 16) * K + koff;
    const ushort_t* gB0 = BTm + (size_t)(col0 + srow) * K + koff;
    const ushort_t* gB1 = BTm + (size_t)(col0 + srow + 16) * K + koff;
    ushort_t* lA0 = As + (wave * 2 + 0) * 512;
    ushort_t* lA1 = As + (wave * 2 + 1) * 512;
    ushort_t* lB0 = Bs + (wave * 2 + 0) * 512;
    ushort_t* lB1 = Bs + (wave * 2 + 1) * 512;

    for (int k0 = 0; k0 < K; k0 += 32) {
        __builtin_amdgcn_global_load_lds(
            (const __attribute__((address_space(1))) void*)(gA0 + k0),
            (__attribute__((address_space(3))) void*)lA0, 16, 0, 0);
        __builtin_amdgcn_global_load_lds(
            (const __attribute__((address_space(1))) void*)(gA1 + k0),
            (__attribute__((address_space(3))) void*)lA1, 16, 0, 0);
        __builtin_amdgcn_global_load_lds(
            (const __attribute__((address_space(1))) void*)(gB0 + k0),
            (__attribute__((address_space(3))) void*)lB0, 16, 0, 0);
        __builtin_amdgcn_global_load_lds(
            (const __attribute__((address_space(1))) void*)(gB1 + k0),
            (__attribute__((address_space(3))) void*)lB1, 16, 0, 0);
        __syncthreads();   // drains vmcnt(0) then barrier -> LDS tile complete

        short8v af[4], bf[4];
        #pragma unroll
        for (int m = 0; m < 4; m++)
            af[m] = *(const short8v*)(As + (wr * 64 + m * 16 + (lane & 15)) * 32 + (lane >> 4) * 8);
        #pragma unroll
        for (int n = 0; n < 4; n++)
            bf[n] = *(const short8v*)(Bs + (wc * 64 + n * 16 + (lane & 15)) * 32 + (lane >> 4) * 8);
        #pragma unroll
        for (int m = 0; m < 4; m++)
            #pragma unroll
            for (int n = 0; n < 4; n++)
                acc[m][n] = __builtin_amdgcn_mfma_f32_16x16x32_bf16(af[m], bf[n], acc[m][n], 0, 0, 0);
        __syncthreads();   // all waves done reading before next stage overwrites
    }

    #pragma unroll
    for (int m = 0; m < 4; m++) {
        #pragma unroll
        for (int n = 0; n < 4; n++) {
            int row = row0 + wr * 64 + m * 16 + (lane >> 4) * 4;
            int col = col0 + wc * 64 + n * 16 + (lane & 15);
            if (col < Nc) {
                #pragma unroll
                for (int e = 0; e < 4; e++)
                    C[(size_t)(row + e) * ldc + col] = acc[m][n][e];
            }
        }
    }
}

// ---------------- conv + silu + split + l2norm + beta/g ----------------
__global__ __launch_bounds__(256) void conv_split_kernel(const float* __restrict__ mixed,
                                                         const float* __restrict__ conv_w,
                                                         const float* __restrict__ A_log,
                                                         const float* __restrict__ dt_bias,
                                                         float* __restrict__ qn,
                                                         float* __restrict__ kn,
                                                         float* __restrict__ vn,
                                                         float* __restrict__ beta,
                                                         float* __restrict__ g) {
    int bt = blockIdx.x;
    int t = bt & (TT - 1);
    int tid = threadIdx.x;
    int c0 = tid * 8;

    float val[8];
    #pragma unroll
    for (int i = 0; i < 8; i++) val[i] = 0.f;
    #pragma unroll
    for (int j = 0; j < KSZ; j++) {
        int tt = t - (KSZ - 1) + j;
        if (tt >= 0) {
            const float* src = mixed + (size_t)(bt - (KSZ - 1) + j) * TOT + c0;
            #pragma unroll
            for (int i = 0; i < 8; i++) val[i] += src[i] * conv_w[(c0 + i) * KSZ + j];
        }
    }
    #pragma unroll
    for (int i = 0; i < 8; i++) val[i] = siluf(val[i]);

    float ss = 0.f;
    #pragma unroll
    for (int i = 0; i < 8; i++) ss += val[i] * val[i];
    #pragma unroll
    for (int m = 1; m < 16; m <<= 1) ss += __shfl_xor(ss, m, 64);
    float rs = rsqrtf(ss + 1e-6f);

    if (tid < 128) {
        float sc = rs * 0.08838834764831845f;
        #pragma unroll
        for (int i = 0; i < 8; i++) qn[(size_t)bt * 1024 + c0 + i] = val[i] * sc;
    } else if (tid < 192) {
        #pragma unroll
        for (int i = 0; i < 8; i++) kn[(size_t)bt * 512 + (c0 - 1024) + i] = val[i] * rs;
    } else {
        #pragma unroll
        for (int i = 0; i < 8; i++) vn[(size_t)bt * 512 + (c0 - 1536) + i] = val[i];
    }
    if (tid < 8) {
        beta[bt * 8 + tid] = sigmoidf_(mixed[(size_t)bt * TOT + 3072 + tid]);
    } else if (tid < 16) {
        int h = tid - 8;
        g[bt * 8 + h] = -expf(A_log[h]) * softplusf_(mixed[(size_t)bt * TOT + 3080 + h] + dt_bias[h]);
    }
}

// ---------------- Phase A: per-chunk UT transform ----------------
__global__ __launch_bounds__(256) void phaseA_kernel(const float* __restrict__ kn,
                                                     const float* __restrict__ vn,
                                                     const float* __restrict__ beta,
                                                     const float* __restrict__ g,
                                                     float* __restrict__ W,
                                                     float* __restrict__ Z,
                                                     float* __restrict__ Bvec) {
    int chunk = blockIdx.x;
    int bh = chunk >> 4, c = chunk & 15;
    int b = bh >> 3, h = bh & 7, hk = h >> 1;
    int bt0 = b * TT + c * CHUNK;
    __shared__ float kc[64][129];
    __shared__ float M[64][65];
    __shared__ float X[64][256];
    __shared__ float Bv[64], Bev[64], bev[64];
    int tid = threadIdx.x;

    if (tid < 64) {
        float v = g[(size_t)(bt0 + tid) * 8 + h];
        #pragma unroll
        for (int off = 1; off < 64; off <<= 1) {
            float n = __shfl_up(v, off, 64);
            if (tid >= off) v += n;
        }
        Bv[tid] = v;
        Bev[tid] = expf(v);
        bev[tid] = beta[(size_t)(bt0 + tid) * 8 + h];
        Bvec[chunk * 64 + tid] = v;
    }
    for (int i = tid; i < 8192; i += 256) {
        int t = i >> 7, r = i & 127;
        kc[t][r] = kn[(size_t)(bt0 + t) * 512 + hk * 128 + r];
    }
    __syncthreads();

    {
        int t = tid & 63, sg = tid >> 6;
        for (int ss = 0; ss < 16; ss++) {
            int s = sg * 16 + ss;
            float acc = 0.f;
            if (s < t) {
                for (int i = 0; i < 128; i++) acc += kc[t][i] * kc[s][i];
                acc *= bev[t] * expf(Bv[t] - Bv[s]);
            }
            M[t][s] = acc;
        }
    }
    for (int i = tid; i < 8192; i += 256) {
        int t = i >> 7, r = i & 127;
        X[t][r]       = bev[t] * vn[(size_t)(bt0 + t) * 512 + hk * 128 + r];
        X[t][128 + r] = bev[t] * Bev[t] * kc[t][r];
    }
    __syncthreads();
    for (int t = 1; t < 64; t++) {
        float acc = 0.f;
        for (int s = 0; s < t; s++) acc += M[t][s] * X[s][tid];
        X[t][tid] -= acc;
        __syncthreads();
    }
    float* Wc = W + (size_t)chunk * 8192;
    float* Zc = Z + (size_t)chunk * 8192;
    for (int i = tid; i < 8192; i += 256) {
        int t = i >> 7, r = i & 127;
        Wc[i] = X[t][r];
        Zc[i] = X[t][128 + r];
    }
}

// ---------------- Phase B: sequential over chunks ----------------
__global__ __launch_bounds__(256) void phaseB_kernel(const float* __restrict__ kn,
                                                     float* __restrict__ WU,
                                                     const float* __restrict__ Z,
                                                     const float* __restrict__ Bvec,
                                                     float* __restrict__ Sall) {
    int bh = blockIdx.x >> 2, cg = blockIdx.x & 3;
    int b = bh >> 3, h = bh & 7, hk = h >> 1;
    __shared__ float Zt[128][65];
    __shared__ float Kl[64][129];
    __shared__ float Sc[128][36];
    __shared__ float Ul[64][36];
    __shared__ float Bv[64];
    int tid = threadIdx.x;

    for (int i = tid; i < 128 * 32; i += 256) Sc[i >> 5][i & 31] = 0.f;

    for (int c = 0; c < NCHUNK; c++) {
        int chunk = bh * 16 + c;
        int bt0 = b * TT + c * CHUNK;
        __syncthreads();
        float* Sg = Sall + (size_t)chunk * 16384 + cg * 32;
        for (int i = tid; i < 128 * 32; i += 256) {
            int r = i >> 5, j = i & 31;
            Sg[(size_t)r * 128 + j] = Sc[r][j];
        }
        if (tid < 64) Bv[tid] = Bvec[chunk * 64 + tid];
        const float* Zc = Z + (size_t)chunk * 8192;
        for (int i = tid; i < 8192; i += 256) Zt[i & 127][i >> 7] = Zc[i];
        __syncthreads();
        float BC = Bv[63];
        float gC = expf(BC);
        for (int i = tid; i < 8192; i += 256) {
            int s = i >> 7, r = i & 127;
            Kl[s][r] = kn[(size_t)(bt0 + s) * 512 + hk * 128 + r] * expf(BC - Bv[s]);
        }
        float* Wc = WU + (size_t)chunk * 8192;
        for (int i = tid; i < 64 * 32; i += 256) {
            int t = i >> 5, j = i & 31;
            Ul[t][j] = Wc[(size_t)t * 128 + cg * 32 + j];
        }
        __syncthreads();
        {
            int tr = tid & 63, tc = tid >> 6;
            int j0 = tc * 8;
            float acc[8] = {};
            for (int kk = 0; kk < 128; kk++) {
                float zv = Zt[kk][tr];
                float4 s0 = *(const float4*)&Sc[kk][j0];
                float4 s1 = *(const float4*)&Sc[kk][j0 + 4];
                acc[0] += zv * s0.x; acc[1] += zv * s0.y; acc[2] += zv * s0.z; acc[3] += zv * s0.w;
                acc[4] += zv * s1.x; acc[5] += zv * s1.y; acc[6] += zv * s1.z; acc[7] += zv * s1.w;
            }
            #pragma unroll
            for (int j = 0; j < 8; j++) Ul[tr][j0 + j] -= acc[j];
        }
        __syncthreads();
        for (int i = tid; i < 64 * 32; i += 256) {
            int t = i >> 5, j = i & 31;
            Wc[(size_t)t * 128 + cg * 32 + j] = Ul[t][j];
        }
        {
            int r = tid & 127, th = tid >> 7;
            int j1 = th * 16;
            float sacc[16];
            #pragma unroll
            for (int j = 0; j < 16; j++) sacc[j] = gC * Sc[r][j1 + j];
            for (int s = 0; s < 64; s++) {
                float kv = Kl[s][r];
                #pragma unroll
                for (int jq = 0; jq < 4; jq++) {
                    float4 uv = *(const float4*)&Ul[s][j1 + jq * 4];
                    sacc[jq * 4 + 0] += kv * uv.x; sacc[jq * 4 + 1] += kv * uv.y;
                    sacc[jq * 4 + 2] += kv * uv.z; sacc[jq * 4 + 3] += kv * uv.w;
                }
            }
            #pragma unroll
            for (int j = 0; j < 16; j++) Sc[r][j1 + j] = sacc[j];
        }
    }
}

// ---------------- Phase C: per-chunk outputs ----------------
__global__ __launch_bounds__(256) void phaseC_kernel(const float* __restrict__ qn,
                                                     const float* __restrict__ kn,
                                                     const float* __restrict__ U,
                                                     const float* __restrict__ Sall,
                                                     const float* __restrict__ Bvec,
                                                     float* __restrict__ o) {
    int chunk = blockIdx.x;
    int bh = chunk >> 4, c = chunk & 15;
    int b = bh >> 3, h = bh & 7, hk = h >> 1;
    int bt0 = b * TT + c * CHUNK;
    __shared__ float qc[64][129];
    __shared__ float kc[64][129];
    __shared__ float P[64][65];
    __shared__ float Bv[64];
    int tid = threadIdx.x;

    if (tid < 64) Bv[tid] = Bvec[chunk * 64 + tid];
    for (int i = tid; i < 8192; i += 256) {
        int t = i >> 7, r = i & 127;
        qc[t][r] = qn[(size_t)(bt0 + t) * 1024 + h * 128 + r];
        kc[t][r] = kn[(size_t)(bt0 + t) * 512 + hk * 128 + r];
    }
    __syncthreads();
    {
        int t = tid & 63, sg = tid >> 6;
        for (int ss = 0; ss < 16; ss++) {
            int s = sg * 16 + ss;
            float acc = 0.f;
            if (s <= t) {
                for (int i = 0; i < 128; i++) acc += qc[t][i] * kc[s][i];
                acc *= expf(Bv[t] - Bv[s]);
            }
            P[t][s] = acc;
        }
    }
    __syncthreads();
    const float* Uc = U + (size_t)chunk * 8192;
    for (int i = tid; i < 8192; i += 256) {
        int t = i >> 7, r = i & 127;
        kc[t][r] = Uc[i];
    }
    __syncthreads();
    {
        int j = tid & 127, tq = tid >> 7;
        const float* Sg = Sall + (size_t)chunk * 16384;
        float acc[32] = {};
        for (int r = 0; r < 128; r++) {
            float sv = Sg[(size_t)r * 128 + j];
            #pragma unroll
            for (int u2 = 0; u2 < 32; u2++) acc[u2] += qc[tq * 32 + u2][r] * sv;
        }
        #pragma unroll
        for (int u2 = 0; u2 < 32; u2++) acc[u2] *= expf(Bv[tq * 32 + u2]);
        for (int s = 0; s < 64; s++) {
            float uv = kc[s][j];
            #pragma unroll
            for (int u2 = 0; u2 < 32; u2++) acc[u2] += P[tq * 32 + u2][s] * uv;
        }
        #pragma unroll
        for (int u2 = 0; u2 < 32; u2++) {
            int t = tq * 32 + u2;
            o[(size_t)(bt0 + t) * 1024 + h * 128 + j] = acc[u2];
        }
    }
}

// ---------------- gated RMS norm + silu(z) gate -> bf16 ----------------
__global__ __launch_bounds__(64) void norm_gate_kernel(const float* __restrict__ o_scan,
                                                       const float* __restrict__ mixed,
                                                       const float* __restrict__ norm_w,
                                                       ushort_t* __restrict__ ginb) {
    int bth = blockIdx.x;
    int bt = bth >> 3, h = bth & 7;
    int lane = threadIdx.x;
    size_t base = (size_t)bt * 1024 + h * 128;
    float o0 = o_scan[base + lane];
    float o1 = o_scan[base + lane + 64];
    float ss = o0 * o0 + o1 * o1;
    #pragma unroll
    for (int m = 1; m < 64; m <<= 1) ss += __shfl_xor(ss, m, 64);
    float r = rsqrtf(ss * (1.f / 128.f) + 1e-5f);
    size_t zbase = (size_t)bt * TOT + 2048 + h * 128;
    float z0 = mixed[zbase + lane];
    float z1 = mixed[zbase + lane + 64];
    ginb[base + lane]      = f2bf(o0 * r * norm_w[lane]      * siluf(z0));
    ginb[base + lane + 64] = f2bf(o1 * r * norm_w[lane + 64] * siluf(z1));
}

extern "C" void kernel_launch(void* const* d_in, const int* in_sizes, int n_in,
                              void* d_out, int out_size, void* d_ws, size_t ws_size,
                              hipStream_t stream) {
    const float* x       = (const float*)d_in[0];
    const float* w_in    = (const float*)d_in[1];
    const float* conv_w  = (const float*)d_in[2];
    const float* A_log   = (const float*)d_in[3];
    const float* dt_bias = (const float*)d_in[4];
    const float* norm_w  = (const float*)d_in[5];
    const float* w_out   = (const float*)d_in[6];
    float* out = (float*)d_out;

    float* ws    = (float*)d_ws;
    float* mixed = ws;                           // 6,324,224 f
    float* qn    = mixed + (size_t)BT * TOT;     // 2,097,152 f
    float* kn    = qn + (size_t)BT * 1024;       // 1,048,576 f
    float* vn    = kn + (size_t)BT * 512;        // 1,048,576 f
    float* beta  = vn + (size_t)BT * 512;        // 16,384 f
    float* gdec  = beta + BT * 8;                // 16,384 f
    float* Wu    = gdec + BT * 8;                // 2,097,152 f
    float* Zz    = Wu + (size_t)BT * 1024;       // 2,097,152 f
    float* Bvec  = Zz + (size_t)BT * 1024;       // 16,384 f
    float* Sall  = Bvec + NBH * NCHUNK * 64;     // 4,194,304 f
    float* bt2f  = Sall + (size_t)16384 * 256;   // 262,144 f (w_out^T bf16)
    float* oscan = Zz;                           // alias: Z dead after phase B

    // bf16 aliases (liveness-disjoint with their hosts):
    ushort_t* xb   = (ushort_t*)Sall;            // x bf16: dead before phaseB writes Sall
    ushort_t* bt1  = (ushort_t*)Wu;              // w_in^T bf16 [3200][1024]: dead before phaseA writes Wu
    ushort_t* bt2  = (ushort_t*)bt2f;            // w_out^T bf16 [1024][1024]: lives to the end
    ushort_t* ginb = (ushort_t*)qn;              // gated bf16 input of GEMM2: qn dead after phaseC

    // 0) converts
    f2bf_kernel<<<(BT * HID) / 1024, 256, 0, stream>>>(x, xb);
    transpose_f2bf<<<dim3(NPAD1 / 32, HID / 32), 256, 0, stream>>>(w_in, bt1, HID, TOT);
    transpose_f2bf<<<dim3(HID / 32, HID / 32), 256, 0, stream>>>(w_out, bt2, HID, HID);

    // 1) mixed = x @ w_in  (bf16 MFMA, N padded to 3200, col-guarded store)
    gemm_bf16<<<dim3(NPAD1 / 128, BT / 128), 256, 0, stream>>>(xb, bt1, mixed, HID, TOT, TOT);

    // 2) conv + silu + split + l2norm + beta/g
    conv_split_kernel<<<BT, 256, 0, stream>>>(mixed, conv_w, A_log, dt_bias, qn, kn, vn, beta, gdec);

    // 3) chunkwise delta-rule scan
    phaseA_kernel<<<NBH * NCHUNK, 256, 0, stream>>>(kn, vn, beta, gdec, Wu, Zz, Bvec);
    phaseB_kernel<<<NBH * 4, 256, 0, stream>>>(kn, Wu, Zz, Bvec, Sall);
    phaseC_kernel<<<NBH * NCHUNK, 256, 0, stream>>>(qn, kn, Wu, Sall, Bvec, oscan);

    // 4) gated RMS norm + silu(z) -> bf16
    norm_gate_kernel<<<BT * NQ, 64, 0, stream>>>(oscan, mixed, norm_w, ginb);

    // 5) out = gin @ w_out  (bf16 MFMA)
    gemm_bf16<<<dim3(HID / 128, BT / 128), 256, 0, stream>>>(ginb, bt2, out, HID, HID, HID);
}

// Round 4
// 298.349 us; speedup vs baseline: 11.5831x; 1.4795x over previous
//
#include <hip/hip_runtime.h>
#include <hip/hip_bf16.h>
#include <math.h>

// Problem constants (from reference)
#define BB    2
#define TT    1024
#define HID   1024
#define NQ    8
#define NK    4
#define DK    128
#define DV    128
#define TOT   3088      // 1024+512+512+1024+8+8
#define CONVD 2048
#define KSZ   4
#define BT    (BB*TT)   // 2048
#define CHUNK 64
#define NCHUNK (TT/CHUNK)   // 16
#define NBH   (BB*NQ)       // 16
#define NPAD1 3200          // 3088 padded to 25*128
#define JW    32            // phaseB column-group width

typedef __attribute__((ext_vector_type(8))) short short8v;
typedef __attribute__((ext_vector_type(4))) float f32x4;
typedef unsigned short ushort_t;
typedef unsigned int uint_t;

__device__ __forceinline__ float siluf(float x)     { return x / (1.f + expf(-x)); }
__device__ __forceinline__ float sigmoidf_(float x) { return 1.f / (1.f + expf(-x)); }
__device__ __forceinline__ float softplusf_(float x){ return x > 15.f ? x : log1pf(expf(x)); }

__device__ __forceinline__ ushort_t f2bf(float f) {
    uint_t u = __builtin_bit_cast(uint_t, f);
    u = (u + 0x7fff + ((u >> 16) & 1)) >> 16;
    return (ushort_t)u;
}
__device__ __forceinline__ float bf2f(ushort_t u) {
    uint_t v = ((uint_t)u) << 16;
    return __builtin_bit_cast(float, v);
}
__device__ __forceinline__ ushort4 pack4(f32x4 v) {
    ushort4 p; p.x = f2bf(v[0]); p.y = f2bf(v[1]); p.z = f2bf(v[2]); p.w = f2bf(v[3]);
    return p;
}

// ---------------- elementwise f32 -> bf16 ----------------
__global__ __launch_bounds__(256) void f2bf_kernel(const float* __restrict__ src,
                                                   ushort_t* __restrict__ dst) {
    int i = (blockIdx.x * 256 + threadIdx.x) * 4;
    float4 v = *(const float4*)(src + i);
    ushort4 o;
    o.x = f2bf(v.x); o.y = f2bf(v.y); o.z = f2bf(v.z); o.w = f2bf(v.w);
    *(ushort4*)(dst + i) = o;
}

// ---------------- tiled transpose + convert: dst[n][k] = bf16(src[k][n]) ----------------
__global__ __launch_bounds__(256) void transpose_f2bf(const float* __restrict__ src,
                                                      ushort_t* __restrict__ dst,
                                                      int K, int N) {
    __shared__ float tile[32][33];
    int n0 = blockIdx.x * 32, k0 = blockIdx.y * 32;
    int c = threadIdx.x & 31, rbase = threadIdx.x >> 5;
    #pragma unroll
    for (int i = 0; i < 4; i++) {
        int r = rbase + i * 8;
        int n = n0 + c;
        tile[r][c] = (n < N) ? src[(size_t)(k0 + r) * N + n] : 0.f;
    }
    __syncthreads();
    #pragma unroll
    for (int i = 0; i < 4; i++) {
        int r = rbase + i * 8;
        dst[(size_t)(n0 + r) * K + k0 + c] = f2bf(tile[c][r]);
    }
}

// ---------------- bf16 MFMA GEMM (m97 structure): C[M,N] = A[M,K] @ BT[N,K]^T ----------------
__global__ __launch_bounds__(256) void gemm_bf16(const ushort_t* __restrict__ A,
                                                 const ushort_t* __restrict__ BTm,
                                                 float* __restrict__ C,
                                                 int K, int Nc, int ldc) {
    __shared__ ushort_t As[128 * 32];
    __shared__ ushort_t Bs[128 * 32];
    int tid = threadIdx.x;
    int wave = tid >> 6, lane = tid & 63;
    int wr = wave >> 1, wc = wave & 1;
    int row0 = blockIdx.y * 128, col0 = blockIdx.x * 128;

    f32x4 zero4 = {0.f, 0.f, 0.f, 0.f};
    f32x4 acc[4][4];
    #pragma unroll
    for (int m = 0; m < 4; m++)
        #pragma unroll
        for (int n = 0; n < 4; n++) acc[m][n] = zero4;

    int srow = wave * 32 + (lane >> 2);
    int koff = (lane & 3) * 8;
    const ushort_t* gA0 = A + (size_t)(row0 + srow) * K + koff;
    const ushort_t* gA1 = A + (size_t)(row0 + srow + 16) * K + koff;
    const ushort_t* gB0 = BTm + (size_t)(col0 + srow) * K + koff;
    const ushort_t* gB1 = BTm + (size_t)(col0 + srow + 16) * K + koff;
    ushort_t* lA0 = As + (wave * 2 + 0) * 512;
    ushort_t* lA1 = As + (wave * 2 + 1) * 512;
    ushort_t* lB0 = Bs + (wave * 2 + 0) * 512;
    ushort_t* lB1 = Bs + (wave * 2 + 1) * 512;

    for (int k0 = 0; k0 < K; k0 += 32) {
        __builtin_amdgcn_global_load_lds(
            (const __attribute__((address_space(1))) void*)(gA0 + k0),
            (__attribute__((address_space(3))) void*)lA0, 16, 0, 0);
        __builtin_amdgcn_global_load_lds(
            (const __attribute__((address_space(1))) void*)(gA1 + k0),
            (__attribute__((address_space(3))) void*)lA1, 16, 0, 0);
        __builtin_amdgcn_global_load_lds(
            (const __attribute__((address_space(1))) void*)(gB0 + k0),
            (__attribute__((address_space(3))) void*)lB0, 16, 0, 0);
        __builtin_amdgcn_global_load_lds(
            (const __attribute__((address_space(1))) void*)(gB1 + k0),
            (__attribute__((address_space(3))) void*)lB1, 16, 0, 0);
        __syncthreads();

        short8v af[4], bf[4];
        #pragma unroll
        for (int m = 0; m < 4; m++)
            af[m] = *(const short8v*)(As + (wr * 64 + m * 16 + (lane & 15)) * 32 + (lane >> 4) * 8);
        #pragma unroll
        for (int n = 0; n < 4; n++)
            bf[n] = *(const short8v*)(Bs + (wc * 64 + n * 16 + (lane & 15)) * 32 + (lane >> 4) * 8);
        #pragma unroll
        for (int m = 0; m < 4; m++)
            #pragma unroll
            for (int n = 0; n < 4; n++)
                acc[m][n] = __builtin_amdgcn_mfma_f32_16x16x32_bf16(af[m], bf[n], acc[m][n], 0, 0, 0);
        __syncthreads();
    }

    #pragma unroll
    for (int m = 0; m < 4; m++) {
        #pragma unroll
        for (int n = 0; n < 4; n++) {
            int row = row0 + wr * 64 + m * 16 + (lane >> 4) * 4;
            int col = col0 + wc * 64 + n * 16 + (lane & 15);
            if (col < Nc) {
                #pragma unroll
                for (int e = 0; e < 4; e++)
                    C[(size_t)(row + e) * ldc + col] = acc[m][n][e];
            }
        }
    }
}

// ---------------- conv + silu + split + l2norm + beta/g ----------------
__global__ __launch_bounds__(256) void conv_split_kernel(const float* __restrict__ mixed,
                                                         const float* __restrict__ conv_w,
                                                         const float* __restrict__ A_log,
                                                         const float* __restrict__ dt_bias,
                                                         float* __restrict__ qn,
                                                         float* __restrict__ kn,
                                                         float* __restrict__ vn,
                                                         float* __restrict__ beta,
                                                         float* __restrict__ g) {
    int bt = blockIdx.x;
    int t = bt & (TT - 1);
    int tid = threadIdx.x;
    int c0 = tid * 8;

    float val[8];
    #pragma unroll
    for (int i = 0; i < 8; i++) val[i] = 0.f;
    #pragma unroll
    for (int j = 0; j < KSZ; j++) {
        int tt = t - (KSZ - 1) + j;
        if (tt >= 0) {
            const float* src = mixed + (size_t)(bt - (KSZ - 1) + j) * TOT + c0;
            #pragma unroll
            for (int i = 0; i < 8; i++) val[i] += src[i] * conv_w[(c0 + i) * KSZ + j];
        }
    }
    #pragma unroll
    for (int i = 0; i < 8; i++) val[i] = siluf(val[i]);

    float ss = 0.f;
    #pragma unroll
    for (int i = 0; i < 8; i++) ss += val[i] * val[i];
    #pragma unroll
    for (int m = 1; m < 16; m <<= 1) ss += __shfl_xor(ss, m, 64);
    float rs = rsqrtf(ss + 1e-6f);

    if (tid < 128) {
        float sc = rs * 0.08838834764831845f;
        #pragma unroll
        for (int i = 0; i < 8; i++) qn[(size_t)bt * 1024 + c0 + i] = val[i] * sc;
    } else if (tid < 192) {
        #pragma unroll
        for (int i = 0; i < 8; i++) kn[(size_t)bt * 512 + (c0 - 1024) + i] = val[i] * rs;
    } else {
        #pragma unroll
        for (int i = 0; i < 8; i++) vn[(size_t)bt * 512 + (c0 - 1536) + i] = val[i];
    }
    if (tid < 8) {
        beta[bt * 8 + tid] = sigmoidf_(mixed[(size_t)bt * TOT + 3072 + tid]);
    } else if (tid < 16) {
        int h = tid - 8;
        g[bt * 8 + h] = -expf(A_log[h]) * softplusf_(mixed[(size_t)bt * TOT + 3080 + h] + dt_bias[h]);
    }
}

// ---------------- Phase A: per-chunk UT transform ----------------
// W = T^-1 diag(beta) V (fp32); Znegb = -T^-1 diag(beta*Gamma) K (bf16);
// knT[bhk][r][t] = bf16(kn) transposed (written once per kv-head).
__global__ __launch_bounds__(256) void phaseA_kernel(const float* __restrict__ kn,
                                                     const float* __restrict__ vn,
                                                     const float* __restrict__ beta,
                                                     const float* __restrict__ g,
                                                     float* __restrict__ W,
                                                     ushort_t* __restrict__ Znegb,
                                                     ushort_t* __restrict__ knT,
                                                     float* __restrict__ Bvec) {
    int chunk = blockIdx.x;
    int bh = chunk >> 4, c = chunk & 15;
    int b = bh >> 3, h = bh & 7, hk = h >> 1;
    int bt0 = b * TT + c * CHUNK;
    __shared__ float kc[64][129];
    __shared__ float M[64][65];
    __shared__ float X[64][256];
    __shared__ float Bv[64], Bev[64], bev[64];
    int tid = threadIdx.x;

    if (tid < 64) {
        float v = g[(size_t)(bt0 + tid) * 8 + h];
        #pragma unroll
        for (int off = 1; off < 64; off <<= 1) {
            float n = __shfl_up(v, off, 64);
            if (tid >= off) v += n;
        }
        Bv[tid] = v;
        Bev[tid] = expf(v);
        bev[tid] = beta[(size_t)(bt0 + tid) * 8 + h];
        Bvec[chunk * 64 + tid] = v;
    }
    for (int i = tid; i < 8192; i += 256) {
        int t = i >> 7, r = i & 127;
        kc[t][r] = kn[(size_t)(bt0 + t) * 512 + hk * 128 + r];
    }
    __syncthreads();

    {
        int t = tid & 63, sg = tid >> 6;
        for (int ss = 0; ss < 16; ss++) {
            int s = sg * 16 + ss;
            float acc = 0.f;
            if (s < t) {
                for (int i = 0; i < 128; i++) acc += kc[t][i] * kc[s][i];
                acc *= bev[t] * expf(Bv[t] - Bv[s]);
            }
            M[t][s] = acc;
        }
    }
    for (int i = tid; i < 8192; i += 256) {
        int t = i >> 7, r = i & 127;
        X[t][r]       = bev[t] * vn[(size_t)(bt0 + t) * 512 + hk * 128 + r];
        X[t][128 + r] = bev[t] * Bev[t] * kc[t][r];
    }
    __syncthreads();
    for (int t = 1; t < 64; t++) {
        float acc = 0.f;
        for (int s = 0; s < t; s++) acc += M[t][s] * X[s][tid];
        X[t][tid] -= acc;
        __syncthreads();
    }
    float* Wc = W + (size_t)chunk * 8192;
    ushort_t* Zc = Znegb + (size_t)chunk * 8192;
    for (int i = tid; i < 8192; i += 256) {
        int t = i >> 7, r = i & 127;
        Wc[i] = X[t][r];
        Zc[i] = f2bf(-X[t][128 + r]);
    }
    // transposed bf16 k for phaseB (one writer per kv-head pair)
    if ((h & 1) == 0) {
        ushort_t* kT = knT + (size_t)(b * 4 + hk) * 131072;
        for (int i = tid; i < 8192; i += 256) {
            int r = i >> 6, tt = i & 63;
            kT[(size_t)r * 1024 + c * 64 + tt] = f2bf(kc[tt][r]);
        }
    }
}

// ---------------- Phase B (MFMA): sequential over chunks, S in fp32 accumulators ----------------
// grid = NBH*4 (bh x 4 col-groups of 32), 256 threads = 4 waves.
// per chunk: U = W + (-Z)*S (MFMA, C=W);  S = gC*S + K_hat^T U (MFMA).
__device__ __forceinline__ int swzSt(int j, int k) {   // St[j][k]: 32x128 bf16
    int a = j * 256 + k * 2;
    return a ^ ((j & 7) << 4);
}
__device__ __forceinline__ int swzUt(int j, int s) {   // Ut[j][s]: 32x64 bf16
    int a = j * 128 + s * 2;
    return a ^ ((j & 7) << 4);
}

__global__ __launch_bounds__(256) void phaseB_mfma(const ushort_t* __restrict__ knT,
                                                   const ushort_t* __restrict__ Znegb,
                                                   float* __restrict__ WU,
                                                   const float* __restrict__ Bvec,
                                                   float* __restrict__ Sall) {
    int bh = blockIdx.x >> 2, cg = blockIdx.x & 3;
    int b = bh >> 3, h = bh & 7, hk = h >> 1;
    int j0 = cg * JW;
    int tid = threadIdx.x;
    int wave = tid >> 6, lane = tid & 63;
    int lr = lane & 15, lg = lane >> 4;

    __shared__ __align__(16) ushort_t St[JW * 128];   // S^T slice, swizzled (8KB)
    __shared__ __align__(16) ushort_t Ut[JW * 64];    // U^T slice, swizzled (4KB)
    __shared__ __align__(16) ushort_t ebs[2][64];     // exp(BC - Bv[s]) bf16, double-buffered
    __shared__ float b63s[2];

    for (int i = tid * 8; i < JW * 128; i += 2048)
        *(int4*)(St + i) = make_int4(0, 0, 0, 0);

    f32x4 Sacc[2][2];   // wave rows [32w,32w+32): fr in {0,1}; cols fc in {0,1}
    #pragma unroll
    for (int fr = 0; fr < 2; fr++)
        #pragma unroll
        for (int fc = 0; fc < 2; fc++) Sacc[fr][fc] = (f32x4){0.f, 0.f, 0.f, 0.f};

    const ushort_t* kTbase = knT + (size_t)(b * 4 + hk) * 131072;

    for (int c = 0; c < NCHUNK; c++) {
        int chunk = bh * 16 + c;
        int cb = c & 1;
        if (tid < 64) {
            float bv = Bvec[chunk * 64 + tid];
            float b63 = Bvec[chunk * 64 + 63];
            ebs[cb][tid] = f2bf(expf(b63 - bv));
            if (tid == 0) b63s[cb] = b63;
        }
        // store S_c (chunk-start state) from accumulators
        float* Sg = Sall + (size_t)chunk * 16384 + j0;
        #pragma unroll
        for (int fr = 0; fr < 2; fr++)
            #pragma unroll
            for (int fc = 0; fc < 2; fc++) {
                int r = wave * 32 + fr * 16 + lg * 4;
                int j = fc * 16 + lr;
                #pragma unroll
                for (int e = 0; e < 4; e++)
                    Sg[(size_t)(r + e) * 128 + j] = Sacc[fr][fc][e];
            }
        __syncthreads();   // B1: St (prev chunk), ebs ready

        // ---- product 1: U = W + (-Z) * S   (wave owns t rows [16w,16w+16))
        int t0 = wave * 16;
        const ushort_t* Zc = Znegb + (size_t)chunk * 8192;
        short8v za[4];
        #pragma unroll
        for (int ks = 0; ks < 4; ks++)
            za[ks] = *(const short8v*)(Zc + (size_t)(t0 + lr) * 128 + ks * 32 + lg * 8);
        float* Wc = WU + (size_t)chunk * 8192 + j0;
        f32x4 Uacc[2];
        #pragma unroll
        for (int fc = 0; fc < 2; fc++) {
            int j = fc * 16 + lr;
            #pragma unroll
            for (int e = 0; e < 4; e++)
                Uacc[fc][e] = Wc[(size_t)(t0 + lg * 4 + e) * 128 + j];
        }
        #pragma unroll
        for (int ks = 0; ks < 4; ks++)
            #pragma unroll
            for (int fc = 0; fc < 2; fc++) {
                short8v sb = *(const short8v*)((const char*)St + swzSt(fc * 16 + lr, ks * 32 + lg * 8));
                Uacc[fc] = __builtin_amdgcn_mfma_f32_16x16x32_bf16(za[ks], sb, Uacc[fc], 0, 0, 0);
            }
        // write U: global (fp32, for phaseC) + LDS transposed bf16
        #pragma unroll
        for (int fc = 0; fc < 2; fc++) {
            int j = fc * 16 + lr;
            #pragma unroll
            for (int e = 0; e < 4; e++)
                Wc[(size_t)(t0 + lg * 4 + e) * 128 + j] = Uacc[fc][e];
            *(ushort4*)((char*)Ut + swzUt(j, t0 + lg * 4)) = pack4(Uacc[fc]);
        }
        // gamma-scale state
        float gC = expf(b63s[cb]);
        #pragma unroll
        for (int fr = 0; fr < 2; fr++)
            #pragma unroll
            for (int fc = 0; fc < 2; fc++)
                #pragma unroll
                for (int e = 0; e < 4; e++) Sacc[fr][fc][e] *= gC;
        __syncthreads();   // B2: Ut ready

        // ---- product 2: S += K_hat^T * U   (wave owns r rows [32w,32w+32))
        const ushort_t* kT = kTbase + c * 64;
        #pragma unroll
        for (int fr = 0; fr < 2; fr++) {
            int r = wave * 32 + fr * 16 + lr;
            #pragma unroll
            for (int ss = 0; ss < 2; ss++) {
                short8v ka = *(const short8v*)(kT + (size_t)r * 1024 + ss * 32 + lg * 8);
                short8v eb = *(const short8v*)(ebs[cb] + ss * 32 + lg * 8);
                short8v a;
                #pragma unroll
                for (int e = 0; e < 8; e++)
                    a[e] = (short)f2bf(bf2f((ushort_t)ka[e]) * bf2f((ushort_t)eb[e]));
                #pragma unroll
                for (int fc = 0; fc < 2; fc++) {
                    short8v ub = *(const short8v*)((const char*)Ut + swzUt(fc * 16 + lr, ss * 32 + lg * 8));
                    Sacc[fr][fc] = __builtin_amdgcn_mfma_f32_16x16x32_bf16(a, ub, Sacc[fr][fc], 0, 0, 0);
                }
            }
        }
        // write S^T bf16 for next chunk's product 1
        #pragma unroll
        for (int fr = 0; fr < 2; fr++)
            #pragma unroll
            for (int fc = 0; fc < 2; fc++) {
                int r = wave * 32 + fr * 16 + lg * 4;
                int j = fc * 16 + lr;
                *(ushort4*)((char*)St + swzSt(j, r)) = pack4(Sacc[fr][fc]);
            }
    }
}

// ---------------- Phase C: per-chunk outputs ----------------
__global__ __launch_bounds__(256) void phaseC_kernel(const float* __restrict__ qn,
                                                     const float* __restrict__ kn,
                                                     const float* __restrict__ U,
                                                     const float* __restrict__ Sall,
                                                     const float* __restrict__ Bvec,
                                                     float* __restrict__ o) {
    int chunk = blockIdx.x;
    int bh = chunk >> 4, c = chunk & 15;
    int b = bh >> 3, h = bh & 7, hk = h >> 1;
    int bt0 = b * TT + c * CHUNK;
    __shared__ float qc[64][129];
    __shared__ float kc[64][129];
    __shared__ float P[64][65];
    __shared__ float Bv[64];
    int tid = threadIdx.x;

    if (tid < 64) Bv[tid] = Bvec[chunk * 64 + tid];
    for (int i = tid; i < 8192; i += 256) {
        int t = i >> 7, r = i & 127;
        qc[t][r] = qn[(size_t)(bt0 + t) * 1024 + h * 128 + r];
        kc[t][r] = kn[(size_t)(bt0 + t) * 512 + hk * 128 + r];
    }
    __syncthreads();
    {
        int t = tid & 63, sg = tid >> 6;
        for (int ss = 0; ss < 16; ss++) {
            int s = sg * 16 + ss;
            float acc = 0.f;
            if (s <= t) {
                for (int i = 0; i < 128; i++) acc += qc[t][i] * kc[s][i];
                acc *= expf(Bv[t] - Bv[s]);
            }
            P[t][s] = acc;
        }
    }
    __syncthreads();
    const float* Uc = U + (size_t)chunk * 8192;
    for (int i = tid; i < 8192; i += 256) {
        int t = i >> 7, r = i & 127;
        kc[t][r] = Uc[i];
    }
    __syncthreads();
    {
        int j = tid & 127, tq = tid >> 7;
        const float* Sg = Sall + (size_t)chunk * 16384;
        float acc[32] = {};
        for (int r = 0; r < 128; r++) {
            float sv = Sg[(size_t)r * 128 + j];
            #pragma unroll
            for (int u2 = 0; u2 < 32; u2++) acc[u2] += qc[tq * 32 + u2][r] * sv;
        }
        #pragma unroll
        for (int u2 = 0; u2 < 32; u2++) acc[u2] *= expf(Bv[tq * 32 + u2]);
        for (int s = 0; s < 64; s++) {
            float uv = kc[s][j];
            #pragma unroll
            for (int u2 = 0; u2 < 32; u2++) acc[u2] += P[tq * 32 + u2][s] * uv;
        }
        #pragma unroll
        for (int u2 = 0; u2 < 32; u2++) {
            int t = tq * 32 + u2;
            o[(size_t)(bt0 + t) * 1024 + h * 128 + j] = acc[u2];
        }
    }
}

// ---------------- gated RMS norm + silu(z) gate -> bf16 ----------------
__global__ __launch_bounds__(64) void norm_gate_kernel(const float* __restrict__ o_scan,
                                                       const float* __restrict__ mixed,
                                                       const float* __restrict__ norm_w,
                                                       ushort_t* __restrict__ ginb) {
    int bth = blockIdx.x;
    int bt = bth >> 3, h = bth & 7;
    int lane = threadIdx.x;
    size_t base = (size_t)bt * 1024 + h * 128;
    float o0 = o_scan[base + lane];
    float o1 = o_scan[base + lane + 64];
    float ss = o0 * o0 + o1 * o1;
    #pragma unroll
    for (int m = 1; m < 64; m <<= 1) ss += __shfl_xor(ss, m, 64);
    float r = rsqrtf(ss * (1.f / 128.f) + 1e-5f);
    size_t zbase = (size_t)bt * TOT + 2048 + h * 128;
    float z0 = mixed[zbase + lane];
    float z1 = mixed[zbase + lane + 64];
    ginb[base + lane]      = f2bf(o0 * r * norm_w[lane]      * siluf(z0));
    ginb[base + lane + 64] = f2bf(o1 * r * norm_w[lane + 64] * siluf(z1));
}

extern "C" void kernel_launch(void* const* d_in, const int* in_sizes, int n_in,
                              void* d_out, int out_size, void* d_ws, size_t ws_size,
                              hipStream_t stream) {
    const float* x       = (const float*)d_in[0];
    const float* w_in    = (const float*)d_in[1];
    const float* conv_w  = (const float*)d_in[2];
    const float* A_log   = (const float*)d_in[3];
    const float* dt_bias = (const float*)d_in[4];
    const float* norm_w  = (const float*)d_in[5];
    const float* w_out   = (const float*)d_in[6];
    float* out = (float*)d_out;

    float* ws    = (float*)d_ws;
    float* mixed = ws;                           // 6,324,224 f
    float* qn    = mixed + (size_t)BT * TOT;     // 2,097,152 f
    float* kn    = qn + (size_t)BT * 1024;       // 1,048,576 f
    float* vn    = kn + (size_t)BT * 512;        // 1,048,576 f
    float* beta  = vn + (size_t)BT * 512;        // 16,384 f
    float* gdec  = beta + BT * 8;                // 16,384 f
    float* Wu    = gdec + BT * 8;                // 2,097,152 f (W -> U, fp32)
    float* Zz    = Wu + (size_t)BT * 1024;       // 2,097,152 f (Znegb+knT bf16 -> oscan)
    float* Bvec  = Zz + (size_t)BT * 1024;       // 16,384 f
    float* Sall  = Bvec + NBH * NCHUNK * 64;     // 4,194,304 f
    float* bt2f  = Sall + (size_t)256 * 16384;   // 524,288 f (w_out^T bf16, 1M ushort)
    float* oscan = Zz;                           // alias: Znegb/knT dead after phaseB

    // bf16 aliases (liveness-disjoint with their hosts):
    ushort_t* xb    = (ushort_t*)Sall;                     // x bf16: dead before phaseB writes Sall
    ushort_t* bt1   = (ushort_t*)Wu;                       // w_in^T bf16: dead before phaseA writes Wu
    ushort_t* bt2   = (ushort_t*)bt2f;                     // w_out^T bf16
    ushort_t* ginb  = (ushort_t*)qn;                       // GEMM2 input: qn dead after phaseC
    ushort_t* Znegb = (ushort_t*)Zz;                       // [256][64][128] bf16 (4MB)
    ushort_t* knTb  = (ushort_t*)(Zz + (size_t)1048576);   // [8][128][1024] bf16 (2MB)

    // 0) converts
    f2bf_kernel<<<(BT * HID) / 1024, 256, 0, stream>>>(x, xb);
    transpose_f2bf<<<dim3(NPAD1 / 32, HID / 32), 256, 0, stream>>>(w_in, bt1, HID, TOT);
    transpose_f2bf<<<dim3(HID / 32, HID / 32), 256, 0, stream>>>(w_out, bt2, HID, HID);

    // 1) mixed = x @ w_in  (bf16 MFMA)
    gemm_bf16<<<dim3(NPAD1 / 128, BT / 128), 256, 0, stream>>>(xb, bt1, mixed, HID, TOT, TOT);

    // 2) conv + silu + split + l2norm + beta/g
    conv_split_kernel<<<BT, 256, 0, stream>>>(mixed, conv_w, A_log, dt_bias, qn, kn, vn, beta, gdec);

    // 3) chunkwise delta-rule scan
    phaseA_kernel<<<NBH * NCHUNK, 256, 0, stream>>>(kn, vn, beta, gdec, Wu, Znegb, knTb, Bvec);
    phaseB_mfma<<<NBH * 4, 256, 0, stream>>>(knTb, Znegb, Wu, Bvec, Sall);
    phaseC_kernel<<<NBH * NCHUNK, 256, 0, stream>>>(qn, kn, Wu, Sall, Bvec, oscan);

    // 4) gated RMS norm + silu(z) -> bf16
    norm_gate_kernel<<<BT * NQ, 64, 0, stream>>>(oscan, mixed, norm_w, ginb);

    // 5) out = gin @ w_out  (bf16 MFMA)
    gemm_bf16<<<dim3(HID / 128, BT / 128), 256, 0, stream>>>(ginb, bt2, out, HID, HID, HID);
}

// Round 6
// 193.557 us; speedup vs baseline: 17.8542x; 1.5414x over previous
//
#include <hip/hip_runtime.h>
#include <hip/hip_bf16.h>
#include <math.h>

// Problem constants (from reference)
#define BB    2
#define TT    1024
#define HID   1024
#define NQ    8
#define NK    4
#define DK    128
#define DV    128
#define TOT   3088      // 1024+512+512+1024+8+8
#define CONVD 2048
#define KSZ   4
#define BT    (BB*TT)   // 2048
#define CHUNK 64
#define NCHUNK (TT/CHUNK)   // 16
#define NBH   (BB*NQ)       // 16
#define NPAD1 3200          // 3088 padded to 25*128
#define JW    32            // phaseB column-group width

typedef __attribute__((ext_vector_type(8))) short short8v;
typedef __attribute__((ext_vector_type(4))) float f32x4;
typedef unsigned short ushort_t;
typedef unsigned int uint_t;

__device__ __forceinline__ float siluf(float x)     { return x / (1.f + expf(-x)); }
__device__ __forceinline__ float sigmoidf_(float x) { return 1.f / (1.f + expf(-x)); }
__device__ __forceinline__ float softplusf_(float x){ return x > 15.f ? x : log1pf(expf(x)); }

__device__ __forceinline__ ushort_t f2bf(float f) {
    uint_t u = __builtin_bit_cast(uint_t, f);
    u = (u + 0x7fff + ((u >> 16) & 1)) >> 16;
    return (ushort_t)u;
}
__device__ __forceinline__ float bf2f(ushort_t u) {
    uint_t v = ((uint_t)u) << 16;
    return __builtin_bit_cast(float, v);
}
__device__ __forceinline__ ushort4 pack4(f32x4 v) {
    ushort4 p; p.x = f2bf(v[0]); p.y = f2bf(v[1]); p.z = f2bf(v[2]); p.w = f2bf(v[3]);
    return p;
}

// ---------------- elementwise f32 -> bf16 ----------------
__global__ __launch_bounds__(256) void f2bf_kernel(const float* __restrict__ src,
                                                   ushort_t* __restrict__ dst) {
    int i = (blockIdx.x * 256 + threadIdx.x) * 4;
    float4 v = *(const float4*)(src + i);
    ushort4 o;
    o.x = f2bf(v.x); o.y = f2bf(v.y); o.z = f2bf(v.z); o.w = f2bf(v.w);
    *(ushort4*)(dst + i) = o;
}

// ---------------- tiled transpose + convert: dst[n][k] = bf16(src[k][n]) ----------------
__global__ __launch_bounds__(256) void transpose_f2bf(const float* __restrict__ src,
                                                      ushort_t* __restrict__ dst,
                                                      int K, int N) {
    __shared__ float tile[32][33];
    int n0 = blockIdx.x * 32, k0 = blockIdx.y * 32;
    int c = threadIdx.x & 31, rbase = threadIdx.x >> 5;
    #pragma unroll
    for (int i = 0; i < 4; i++) {
        int r = rbase + i * 8;
        int n = n0 + c;
        tile[r][c] = (n < N) ? src[(size_t)(k0 + r) * N + n] : 0.f;
    }
    __syncthreads();
    #pragma unroll
    for (int i = 0; i < 4; i++) {
        int r = rbase + i * 8;
        dst[(size_t)(n0 + r) * K + k0 + c] = f2bf(tile[c][r]);
    }
}

// ---------------- bf16 MFMA GEMM (m97 structure): C[M,N] = A[M,K] @ BT[N,K]^T ----------------
__global__ __launch_bounds__(256) void gemm_bf16(const ushort_t* __restrict__ A,
                                                 const ushort_t* __restrict__ BTm,
                                                 float* __restrict__ C,
                                                 int K, int Nc, int ldc) {
    __shared__ ushort_t As[128 * 32];
    __shared__ ushort_t Bs[128 * 32];
    int tid = threadIdx.x;
    int wave = tid >> 6, lane = tid & 63;
    int wr = wave >> 1, wc = wave & 1;
    int row0 = blockIdx.y * 128, col0 = blockIdx.x * 128;

    f32x4 zero4 = {0.f, 0.f, 0.f, 0.f};
    f32x4 acc[4][4];
    #pragma unroll
    for (int m = 0; m < 4; m++)
        #pragma unroll
        for (int n = 0; n < 4; n++) acc[m][n] = zero4;

    int srow = wave * 32 + (lane >> 2);
    int koff = (lane & 3) * 8;
    const ushort_t* gA0 = A + (size_t)(row0 + srow) * K + koff;
    const ushort_t* gA1 = A + (size_t)(row0 + srow + 16) * K + koff;
    const ushort_t* gB0 = BTm + (size_t)(col0 + srow) * K + koff;
    const ushort_t* gB1 = BTm + (size_t)(col0 + srow + 16) * K + koff;
    ushort_t* lA0 = As + (wave * 2 + 0) * 512;
    ushort_t* lA1 = As + (wave * 2 + 1) * 512;
    ushort_t* lB0 = Bs + (wave * 2 + 0) * 512;
    ushort_t* lB1 = Bs + (wave * 2 + 1) * 512;

    for (int k0 = 0; k0 < K; k0 += 32) {
        __builtin_amdgcn_global_load_lds(
            (const __attribute__((address_space(1))) void*)(gA0 + k0),
            (__attribute__((address_space(3))) void*)lA0, 16, 0, 0);
        __builtin_amdgcn_global_load_lds(
            (const __attribute__((address_space(1))) void*)(gA1 + k0),
            (__attribute__((address_space(3))) void*)lA1, 16, 0, 0);
        __builtin_amdgcn_global_load_lds(
            (const __attribute__((address_space(1))) void*)(gB0 + k0),
            (__attribute__((address_space(3))) void*)lB0, 16, 0, 0);
        __builtin_amdgcn_global_load_lds(
            (const __attribute__((address_space(1))) void*)(gB1 + k0),
            (__attribute__((address_space(3))) void*)lB1, 16, 0, 0);
        __syncthreads();

        short8v af[4], bf[4];
        #pragma unroll
        for (int m = 0; m < 4; m++)
            af[m] = *(const short8v*)(As + (wr * 64 + m * 16 + (lane & 15)) * 32 + (lane >> 4) * 8);
        #pragma unroll
        for (int n = 0; n < 4; n++)
            bf[n] = *(const short8v*)(Bs + (wc * 64 + n * 16 + (lane & 15)) * 32 + (lane >> 4) * 8);
        #pragma unroll
        for (int m = 0; m < 4; m++)
            #pragma unroll
            for (int n = 0; n < 4; n++)
                acc[m][n] = __builtin_amdgcn_mfma_f32_16x16x32_bf16(af[m], bf[n], acc[m][n], 0, 0, 0);
        __syncthreads();
    }

    #pragma unroll
    for (int m = 0; m < 4; m++) {
        #pragma unroll
        for (int n = 0; n < 4; n++) {
            int row = row0 + wr * 64 + m * 16 + (lane >> 4) * 4;
            int col = col0 + wc * 64 + n * 16 + (lane & 15);
            if (col < Nc) {
                #pragma unroll
                for (int e = 0; e < 4; e++)
                    C[(size_t)(row + e) * ldc + col] = acc[m][n][e];
            }
        }
    }
}

// ---------------- conv + silu + split + l2norm + beta/g ----------------
// outputs: qb (bf16), kb (bf16), kn (f32), vn (f32), beta, g
__global__ __launch_bounds__(256) void conv_split_kernel(const float* __restrict__ mixed,
                                                         const float* __restrict__ conv_w,
                                                         const float* __restrict__ A_log,
                                                         const float* __restrict__ dt_bias,
                                                         ushort_t* __restrict__ qb,
                                                         ushort_t* __restrict__ kb,
                                                         float* __restrict__ kn,
                                                         float* __restrict__ vn,
                                                         float* __restrict__ beta,
                                                         float* __restrict__ g) {
    int bt = blockIdx.x;
    int t = bt & (TT - 1);
    int tid = threadIdx.x;
    int c0 = tid * 8;

    float val[8];
    #pragma unroll
    for (int i = 0; i < 8; i++) val[i] = 0.f;
    #pragma unroll
    for (int j = 0; j < KSZ; j++) {
        int tt = t - (KSZ - 1) + j;
        if (tt >= 0) {
            const float* src = mixed + (size_t)(bt - (KSZ - 1) + j) * TOT + c0;
            #pragma unroll
            for (int i = 0; i < 8; i++) val[i] += src[i] * conv_w[(c0 + i) * KSZ + j];
        }
    }
    #pragma unroll
    for (int i = 0; i < 8; i++) val[i] = siluf(val[i]);

    float ss = 0.f;
    #pragma unroll
    for (int i = 0; i < 8; i++) ss += val[i] * val[i];
    #pragma unroll
    for (int m = 1; m < 16; m <<= 1) ss += __shfl_xor(ss, m, 64);
    float rs = rsqrtf(ss + 1e-6f);

    if (tid < 128) {                      // q -> l2norm * DK^-0.5, bf16 only
        float sc = rs * 0.08838834764831845f;
        short8v pk;
        #pragma unroll
        for (int i = 0; i < 8; i++) pk[i] = (short)f2bf(val[i] * sc);
        *(short8v*)(qb + (size_t)bt * 1024 + c0) = pk;
    } else if (tid < 192) {               // k -> l2norm, f32 + bf16
        int o = c0 - 1024;
        short8v pk;
        #pragma unroll
        for (int i = 0; i < 8; i++) {
            float kv = val[i] * rs;
            kn[(size_t)bt * 512 + o + i] = kv;
            pk[i] = (short)f2bf(kv);
        }
        *(short8v*)(kb + (size_t)bt * 512 + o) = pk;
    } else {                              // v -> silu only, f32
        #pragma unroll
        for (int i = 0; i < 8; i++) vn[(size_t)bt * 512 + (c0 - 1536) + i] = val[i];
    }
    if (tid < 8) {
        beta[bt * 8 + tid] = sigmoidf_(mixed[(size_t)bt * TOT + 3072 + tid]);
    } else if (tid < 16) {
        int h = tid - 8;
        g[bt * 8 + h] = -expf(A_log[h]) * softplusf_(mixed[(size_t)bt * TOT + 3080 + h] + dt_bias[h]);
    }
}

// ---------------- Phase A: per-chunk UT transform (MFMA M, register substitution) ----------------
// W = T^-1 diag(beta) V (fp32); Znegb = -T^-1 diag(beta*Gamma) K (bf16); knT bf16 transposed k.
__global__ __launch_bounds__(256) void phaseA_kernel(const float* __restrict__ kn,
                                                     const float* __restrict__ vn,
                                                     const float* __restrict__ beta,
                                                     const float* __restrict__ g,
                                                     float* __restrict__ W,
                                                     ushort_t* __restrict__ Znegb,
                                                     ushort_t* __restrict__ knT,
                                                     float* __restrict__ Bvec) {
    int chunk = blockIdx.x;
    int bh = chunk >> 4, c = chunk & 15;
    int b = bh >> 3, h = bh & 7, hk = h >> 1;
    int bt0 = b * TT + c * CHUNK;
    int tid = threadIdx.x;
    int wave = tid >> 6, lane = tid & 63;
    int lr = lane & 15, lg = lane >> 4;

    __shared__ __align__(16) ushort_t kcb[64 * 128];  // bf16 k, XOR-swizzled rows
    __shared__ float Ms[64][65];
    __shared__ float Bv[64], Bev[64], bev[64];

    if (tid < 64) {   // wave 0: cumulative log-decay scan
        float v = g[(size_t)(bt0 + tid) * 8 + h];
        #pragma unroll
        for (int off = 1; off < 64; off <<= 1) {
            float n = __shfl_up(v, off, 64);
            if (tid >= off) v += n;
        }
        Bv[tid] = v;
        Bev[tid] = expf(v);
        bev[tid] = beta[(size_t)(bt0 + tid) * 8 + h];
        Bvec[chunk * 64 + tid] = v;
    }
    // stage k as bf16, swizzled: byte (r*256 + k*2) ^ ((r&7)<<4)
    for (int i = tid; i < 1024; i += 256) {
        int r = i >> 4, k16 = i & 15;
        const float* src = kn + (size_t)(bt0 + r) * 512 + hk * 128 + k16 * 8;
        float4 v0 = *(const float4*)src;
        float4 v1 = *(const float4*)(src + 4);
        short8v pk;
        pk[0] = (short)f2bf(v0.x); pk[1] = (short)f2bf(v0.y);
        pk[2] = (short)f2bf(v0.z); pk[3] = (short)f2bf(v0.w);
        pk[4] = (short)f2bf(v1.x); pk[5] = (short)f2bf(v1.y);
        pk[6] = (short)f2bf(v1.z); pk[7] = (short)f2bf(v1.w);
        int a = (r * 256 + k16 * 16) ^ ((r & 7) << 4);
        *(short8v*)((char*)kcb + a) = pk;
    }
    __syncthreads();

    // M via MFMA: wave w -> rows [16w,16w+16), s-bands 0..w
    {
        int t_lane = wave * 16 + lr;
        short8v af[4];
        #pragma unroll
        for (int ks = 0; ks < 4; ks++) {
            int a = (t_lane * 256 + ks * 64 + lg * 16) ^ ((t_lane & 7) << 4);
            af[ks] = *(const short8v*)((const char*)kcb + a);
        }
        for (int sb = 0; sb <= wave; sb++) {
            f32x4 macc = {0.f, 0.f, 0.f, 0.f};
            int s_lane = sb * 16 + lr;
            #pragma unroll
            for (int ks = 0; ks < 4; ks++) {
                int a = (s_lane * 256 + ks * 64 + lg * 16) ^ ((s_lane & 7) << 4);
                short8v bfr = *(const short8v*)((const char*)kcb + a);
                macc = __builtin_amdgcn_mfma_f32_16x16x32_bf16(af[ks], bfr, macc, 0, 0, 0);
            }
            #pragma unroll
            for (int e = 0; e < 4; e++) {
                int trow = wave * 16 + lg * 4 + e;
                int scol = sb * 16 + lr;
                Ms[trow][scol] = (scol < trow) ? macc[e] * bev[trow] * expf(Bv[trow] - Bv[scol]) : 0.f;
            }
        }
    }

    // X init in registers: col tid<128 -> beta*v ; col tid>=128 -> beta*Gamma*k
    float Xr[64];
    if (tid < 128) {
        #pragma unroll
        for (int t = 0; t < 64; t++)
            Xr[t] = bev[t] * vn[(size_t)(bt0 + t) * 512 + hk * 128 + tid];
    } else {
        int r = tid - 128;
        #pragma unroll
        for (int t = 0; t < 64; t++)
            Xr[t] = bev[t] * Bev[t] * kn[(size_t)(bt0 + t) * 512 + hk * 128 + r];
    }
    __syncthreads();   // Ms ready

    // forward substitution, column-private, zero barriers, static indexing
    #pragma unroll
    for (int t = 1; t < 64; t++) {
        float a0 = 0.f, a1 = 0.f, a2 = 0.f, a3 = 0.f;
        #pragma unroll
        for (int s = 0; s + 4 <= t; s += 4) {
            a0 += Ms[t][s] * Xr[s];     a1 += Ms[t][s + 1] * Xr[s + 1];
            a2 += Ms[t][s + 2] * Xr[s + 2]; a3 += Ms[t][s + 3] * Xr[s + 3];
        }
        #pragma unroll
        for (int s = t & ~3; s < t; s++) a0 += Ms[t][s] * Xr[s];
        Xr[t] -= (a0 + a1) + (a2 + a3);
    }

    if (tid < 128) {
        float* Wc = W + (size_t)chunk * 8192 + tid;
        #pragma unroll
        for (int t = 0; t < 64; t++) Wc[t * 128] = Xr[t];
    } else {
        ushort_t* Zc = Znegb + (size_t)chunk * 8192 + (tid - 128);
        #pragma unroll
        for (int t = 0; t < 64; t++) Zc[t * 128] = f2bf(-Xr[t]);
    }

    // transposed bf16 k for phaseB (one writer per kv-head pair)
    if ((h & 1) == 0) {
        ushort_t* kT = knT + (size_t)(b * 4 + hk) * 131072 + c * 64;
        for (int i = tid; i < 8192; i += 256) {
            int r = i >> 6, tt = i & 63;
            int a = (tt * 256 + r * 2) ^ ((tt & 7) << 4);
            kT[(size_t)r * 1024 + tt] = *(const ushort_t*)((const char*)kcb + a);
        }
    }
}

// ---------------- Phase B (MFMA): sequential over chunks, S in fp32 accumulators ----------------
__device__ __forceinline__ int swzSt(int j, int k) {   // St[j][k]: 32x128 bf16
    int a = j * 256 + k * 2;
    return a ^ ((j & 7) << 4);
}
__device__ __forceinline__ int swzUt(int j, int s) {   // Ut[j][s]: 32x64 bf16
    int a = j * 128 + s * 2;
    return a ^ ((j & 7) << 4);
}

__global__ __launch_bounds__(256) void phaseB_mfma(const ushort_t* __restrict__ knT,
                                                   const ushort_t* __restrict__ Znegb,
                                                   const float* __restrict__ W,
                                                   const float* __restrict__ Bvec,
                                                   ushort_t* __restrict__ SallT,
                                                   ushort_t* __restrict__ UTg) {
    int bh = blockIdx.x >> 2, cg = blockIdx.x & 3;
    int b = bh >> 3, h = bh & 7, hk = h >> 1;
    int j0 = cg * JW;
    int tid = threadIdx.x;
    int wave = tid >> 6, lane = tid & 63;
    int lr = lane & 15, lg = lane >> 4;

    __shared__ __align__(16) ushort_t St[JW * 128];
    __shared__ __align__(16) ushort_t Ut[JW * 64];
    __shared__ __align__(16) ushort_t ebs[2][64];
    __shared__ float b63s[2];

    for (int i = tid * 8; i < JW * 128; i += 2048)
        *(int4*)(St + i) = make_int4(0, 0, 0, 0);

    f32x4 Sacc[2][2];
    #pragma unroll
    for (int fr = 0; fr < 2; fr++)
        #pragma unroll
        for (int fc = 0; fc < 2; fc++) Sacc[fr][fc] = (f32x4){0.f, 0.f, 0.f, 0.f};

    const ushort_t* kTbase = knT + (size_t)(b * 4 + hk) * 131072;

    for (int c = 0; c < NCHUNK; c++) {
        int chunk = bh * 16 + c;
        int cb = c & 1;
        if (tid < 64) {
            float bv = Bvec[chunk * 64 + tid];
            float b63 = Bvec[chunk * 64 + 63];
            ebs[cb][tid] = f2bf(expf(b63 - bv));
            if (tid == 0) b63s[cb] = b63;
        }
        // store S_c (chunk-start state) as bf16 transposed [j][r]
        ushort_t* SgT = SallT + (size_t)chunk * 16384;
        #pragma unroll
        for (int fr = 0; fr < 2; fr++)
            #pragma unroll
            for (int fc = 0; fc < 2; fc++) {
                int r0 = wave * 32 + fr * 16 + lg * 4;
                int j = j0 + fc * 16 + lr;
                *(ushort4*)(SgT + (size_t)j * 128 + r0) = pack4(Sacc[fr][fc]);
            }
        __syncthreads();   // B1: St (prev chunk), ebs ready

        // ---- product 1: U = W + (-Z) * S
        int t0 = wave * 16;
        const ushort_t* Zc = Znegb + (size_t)chunk * 8192;
        short8v za[4];
        #pragma unroll
        for (int ks = 0; ks < 4; ks++)
            za[ks] = *(const short8v*)(Zc + (size_t)(t0 + lr) * 128 + ks * 32 + lg * 8);
        const float* Wc = W + (size_t)chunk * 8192 + j0;
        f32x4 Uacc[2];
        #pragma unroll
        for (int fc = 0; fc < 2; fc++) {
            int j = fc * 16 + lr;
            #pragma unroll
            for (int e = 0; e < 4; e++)
                Uacc[fc][e] = Wc[(size_t)(t0 + lg * 4 + e) * 128 + j];
        }
        #pragma unroll
        for (int ks = 0; ks < 4; ks++)
            #pragma unroll
            for (int fc = 0; fc < 2; fc++) {
                short8v sb = *(const short8v*)((const char*)St + swzSt(fc * 16 + lr, ks * 32 + lg * 8));
                Uacc[fc] = __builtin_amdgcn_mfma_f32_16x16x32_bf16(za[ks], sb, Uacc[fc], 0, 0, 0);
            }
        // write U: global bf16 transposed [j][t] + LDS transposed bf16
        ushort_t* UTc = UTg + (size_t)chunk * 8192;
        #pragma unroll
        for (int fc = 0; fc < 2; fc++) {
            int jl = fc * 16 + lr;
            ushort4 pu = pack4(Uacc[fc]);
            *(ushort4*)(UTc + (size_t)(j0 + jl) * 64 + t0 + lg * 4) = pu;
            *(ushort4*)((char*)Ut + swzUt(jl, t0 + lg * 4)) = pu;
        }
        // gamma-scale state
        float gC = expf(b63s[cb]);
        #pragma unroll
        for (int fr = 0; fr < 2; fr++)
            #pragma unroll
            for (int fc = 0; fc < 2; fc++)
                #pragma unroll
                for (int e = 0; e < 4; e++) Sacc[fr][fc][e] *= gC;
        __syncthreads();   // B2: Ut ready

        // ---- product 2: S += K_hat^T * U
        const ushort_t* kT = kTbase + c * 64;
        #pragma unroll
        for (int fr = 0; fr < 2; fr++) {
            int r = wave * 32 + fr * 16 + lr;
            #pragma unroll
            for (int ss = 0; ss < 2; ss++) {
                short8v ka = *(const short8v*)(kT + (size_t)r * 1024 + ss * 32 + lg * 8);
                short8v eb = *(const short8v*)(ebs[cb] + ss * 32 + lg * 8);
                short8v a;
                #pragma unroll
                for (int e = 0; e < 8; e++)
                    a[e] = (short)f2bf(bf2f((ushort_t)ka[e]) * bf2f((ushort_t)eb[e]));
                #pragma unroll
                for (int fc = 0; fc < 2; fc++) {
                    short8v ub = *(const short8v*)((const char*)Ut + swzUt(fc * 16 + lr, ss * 32 + lg * 8));
                    Sacc[fr][fc] = __builtin_amdgcn_mfma_f32_16x16x32_bf16(a, ub, Sacc[fr][fc], 0, 0, 0);
                }
            }
        }
        // write S^T bf16 for next chunk's product 1
        #pragma unroll
        for (int fr = 0; fr < 2; fr++)
            #pragma unroll
            for (int fc = 0; fc < 2; fc++) {
                int r = wave * 32 + fr * 16 + lg * 4;
                int j = fc * 16 + lr;
                *(ushort4*)((char*)St + swzSt(j, r)) = pack4(Sacc[fr][fc]);
            }
    }
}

// ---------------- Phase C (MFMA): O = Gamma*(Q S) + P~ U ----------------
__global__ __launch_bounds__(256) void phaseC_mfma(const ushort_t* __restrict__ qb,
                                                   const ushort_t* __restrict__ kb,
                                                   const ushort_t* __restrict__ UTg,
                                                   const ushort_t* __restrict__ SallT,
                                                   const float* __restrict__ Bvec,
                                                   float* __restrict__ o) {
    int chunk = blockIdx.x;
    int bh = chunk >> 4, c = chunk & 15;
    int b = bh >> 3, h = bh & 7, hk = h >> 1;
    int bt0 = b * TT + c * CHUNK;
    int tid = threadIdx.x, wave = tid >> 6, lane = tid & 63;
    int lr = lane & 15, lg = lane >> 4;

    __shared__ float Bv[64], Bev[64];
    __shared__ __align__(16) ushort_t Pb[64 * 64];   // P~ bf16, swizzled

    if (tid < 64) { float v = Bvec[chunk * 64 + tid]; Bv[tid] = v; Bev[tid] = expf(v); }
    __syncthreads();

    int t_lane = wave * 16 + lr;
    const ushort_t* qrow = qb + (size_t)(bt0 + t_lane) * 1024 + h * 128;
    short8v qa[4];
    #pragma unroll
    for (int ks = 0; ks < 4; ks++) qa[ks] = *(const short8v*)(qrow + ks * 32 + lg * 8);

    // ---- P = mask(exp(Bt-Bs) * Q K^T): wave w -> rows [16w,16w+16), all 4 s-bands
    #pragma unroll
    for (int sb = 0; sb < 4; sb++) {
        f32x4 pacc = {0.f, 0.f, 0.f, 0.f};
        const ushort_t* krow = kb + (size_t)(bt0 + sb * 16 + lr) * 512 + hk * 128;
        #pragma unroll
        for (int ks = 0; ks < 4; ks++) {
            short8v kf = *(const short8v*)(krow + ks * 32 + lg * 8);
            pacc = __builtin_amdgcn_mfma_f32_16x16x32_bf16(qa[ks], kf, pacc, 0, 0, 0);
        }
        int scol = sb * 16 + lr;
        #pragma unroll
        for (int e = 0; e < 4; e++) {
            int trow = wave * 16 + lg * 4 + e;
            float val = (scol <= trow) ? pacc[e] * expf(Bv[trow] - Bv[scol]) : 0.f;
            int a = (trow * 128 + scol * 2) ^ ((trow & 7) << 4);
            *(ushort_t*)((char*)Pb + a) = f2bf(val);
        }
    }

    // ---- QS: acc[n] = Q @ S (B-frags straight from global SallT), then scale by Gamma
    float Ge[4];
    #pragma unroll
    for (int e = 0; e < 4; e++) Ge[e] = Bev[wave * 16 + lg * 4 + e];
    const ushort_t* ST = SallT + (size_t)chunk * 16384;
    f32x4 acc[8];
    #pragma unroll
    for (int n = 0; n < 8; n++) {
        acc[n] = (f32x4){0.f, 0.f, 0.f, 0.f};
        int j = n * 16 + lr;
        #pragma unroll
        for (int rs = 0; rs < 4; rs++) {
            short8v sf = *(const short8v*)(ST + (size_t)j * 128 + rs * 32 + lg * 8);
            acc[n] = __builtin_amdgcn_mfma_f32_16x16x32_bf16(qa[rs], sf, acc[n], 0, 0, 0);
        }
        #pragma unroll
        for (int e = 0; e < 4; e++) acc[n][e] *= Ge[e];
    }
    __syncthreads();   // Pb ready

    // ---- acc += P~ @ U (A-frags from Pb LDS, B-frags from global UT)
    short8v pa[2];
    #pragma unroll
    for (int ks = 0; ks < 2; ks++) {
        int a = (t_lane * 128 + (ks * 32 + lg * 8) * 2) ^ ((t_lane & 7) << 4);
        pa[ks] = *(const short8v*)((const char*)Pb + a);
    }
    const ushort_t* UTc = UTg + (size_t)chunk * 8192;
    #pragma unroll
    for (int n = 0; n < 8; n++) {
        int j = n * 16 + lr;
        #pragma unroll
        for (int ks = 0; ks < 2; ks++) {
            short8v uf = *(const short8v*)(UTc + (size_t)j * 64 + ks * 32 + lg * 8);
            acc[n] = __builtin_amdgcn_mfma_f32_16x16x32_bf16(pa[ks], uf, acc[n], 0, 0, 0);
        }
    }
    #pragma unroll
    for (int n = 0; n < 8; n++) {
        int j = n * 16 + lr;
        #pragma unroll
        for (int e = 0; e < 4; e++) {
            int t = wave * 16 + lg * 4 + e;
            o[(size_t)(bt0 + t) * 1024 + h * 128 + j] = acc[n][e];
        }
    }
}

// ---------------- gated RMS norm + silu(z) gate -> bf16 ----------------
__global__ __launch_bounds__(64) void norm_gate_kernel(const float* __restrict__ o_scan,
                                                       const float* __restrict__ mixed,
                                                       const float* __restrict__ norm_w,
                                                       ushort_t* __restrict__ ginb) {
    int bth = blockIdx.x;
    int bt = bth >> 3, h = bth & 7;
    int lane = threadIdx.x;
    size_t base = (size_t)bt * 1024 + h * 128;
    float o0 = o_scan[base + lane];
    float o1 = o_scan[base + lane + 64];
    float ss = o0 * o0 + o1 * o1;
    #pragma unroll
    for (int m = 1; m < 64; m <<= 1) ss += __shfl_xor(ss, m, 64);
    float r = rsqrtf(ss * (1.f / 128.f) + 1e-5f);
    size_t zbase = (size_t)bt * TOT + 2048 + h * 128;
    float z0 = mixed[zbase + lane];
    float z1 = mixed[zbase + lane + 64];
    ginb[base + lane]      = f2bf(o0 * r * norm_w[lane]      * siluf(z0));
    ginb[base + lane + 64] = f2bf(o1 * r * norm_w[lane + 64] * siluf(z1));
}

extern "C" void kernel_launch(void* const* d_in, const int* in_sizes, int n_in,
                              void* d_out, int out_size, void* d_ws, size_t ws_size,
                              hipStream_t stream) {
    const float* x       = (const float*)d_in[0];
    const float* w_in    = (const float*)d_in[1];
    const float* conv_w  = (const float*)d_in[2];
    const float* A_log   = (const float*)d_in[3];
    const float* dt_bias = (const float*)d_in[4];
    const float* norm_w  = (const float*)d_in[5];
    const float* w_out   = (const float*)d_in[6];
    float* out = (float*)d_out;

    // Workspace map (units: FLOATS; bf16 buffers take elem_count/2 floats!)
    float* ws = (float*)d_ws;
    float* mixed = ws;                              // 6,324,224 f   [2048][3088] f32
    float* kn    = mixed + (size_t)BT * TOT;        // 1,048,576 f   [2048][512] f32
    float* vn    = kn + (size_t)BT * 512;           // 1,048,576 f   [2048][512] f32
    float* beta  = vn + (size_t)BT * 512;           // 16,384 f
    float* gdec  = beta + BT * 8;                   // 16,384 f
    float* Wu    = gdec + BT * 8;                   // 2,097,152 f   W [256][64][128] f32; oscan alias
    float* Bvec  = Wu + (size_t)BT * 1024;          // 16,384 f
    float* qbf   = Bvec + NBH * NCHUNK * 64;        // 1,048,576 f   qb: 2048*1024 bf16 = 2,097,152 us
    float* kbf   = qbf + 1048576;                   // 524,288 f     kb: 2048*512 bf16 = 1,048,576 us
    float* knTf  = kbf + 524288;                    // 524,288 f     knT: 8*128*1024 us  ┐
    float* Znf   = knTf + 524288;                   // 1,048,576 f   Zneg: 256*8192 us   │ bt1 spans these
    float* UTf   = Znf + 1048576;                   // 1,048,576 f   UT: 256*8192 us     ┘ (+64K f of UTf)
    float* SallTf= UTf + 1048576;                   // 2,097,152 f   SallT: 256*16384 us; xb alias
    float* bt2f  = SallTf + 2097152;                // 524,288 f     w_out^T: 1024*1024 us
    // total: 17,383,424 f = 69.5 MB (< 77.9 MB high-water proven in round 4)

    ushort_t* qb    = (ushort_t*)qbf;
    ushort_t* kb    = (ushort_t*)kbf;
    ushort_t* knTb  = (ushort_t*)knTf;
    ushort_t* Znegb = (ushort_t*)Znf;
    ushort_t* UTb   = (ushort_t*)UTf;
    ushort_t* SallT = (ushort_t*)SallTf;
    ushort_t* bt2   = (ushort_t*)bt2f;
    // liveness-disjoint aliases:
    ushort_t* xb    = (ushort_t*)SallTf;            // x bf16 (1,048,576 f): dead before phaseB writes SallT
    ushort_t* bt1   = (ushort_t*)knTf;              // w_in^T bf16 (1,638,400 f): dead after GEMM1,
                                                    //   before phaseA writes knT/Zneg & phaseB writes UT
    ushort_t* ginb  = (ushort_t*)qbf;               // GEMM2 input (1,048,576 f): qb dead after phaseC
    float* oscan    = Wu;                           // phaseC out: W dead after phaseB

    // 0) converts
    f2bf_kernel<<<(BT * HID) / 1024, 256, 0, stream>>>(x, xb);
    transpose_f2bf<<<dim3(NPAD1 / 32, HID / 32), 256, 0, stream>>>(w_in, bt1, HID, TOT);
    transpose_f2bf<<<dim3(HID / 32, HID / 32), 256, 0, stream>>>(w_out, bt2, HID, HID);

    // 1) mixed = x @ w_in  (bf16 MFMA)
    gemm_bf16<<<dim3(NPAD1 / 128, BT / 128), 256, 0, stream>>>(xb, bt1, mixed, HID, TOT, TOT);

    // 2) conv + silu + split + l2norm + beta/g
    conv_split_kernel<<<BT, 256, 0, stream>>>(mixed, conv_w, A_log, dt_bias, qb, kb, kn, vn, beta, gdec);

    // 3) chunkwise delta-rule scan
    phaseA_kernel<<<NBH * NCHUNK, 256, 0, stream>>>(kn, vn, beta, gdec, Wu, Znegb, knTb, Bvec);
    phaseB_mfma<<<NBH * 4, 256, 0, stream>>>(knTb, Znegb, Wu, Bvec, SallT, UTb);
    phaseC_mfma<<<NBH * NCHUNK, 256, 0, stream>>>(qb, kb, UTb, SallT, Bvec, oscan);

    // 4) gated RMS norm + silu(z) -> bf16
    norm_gate_kernel<<<BT * NQ, 64, 0, stream>>>(oscan, mixed, norm_w, ginb);

    // 5) out = gin @ w_out  (bf16 MFMA)
    gemm_bf16<<<dim3(HID / 128, BT / 128), 256, 0, stream>>>(ginb, bt2, out, HID, HID, HID);
}

// Round 7
// 186.161 us; speedup vs baseline: 18.5635x; 1.0397x over previous
//
#include <hip/hip_runtime.h>
#include <hip/hip_bf16.h>
#include <math.h>

// Problem constants (from reference)
#define BB    2
#define TT    1024
#define HID   1024
#define NQ    8
#define NK    4
#define DK    128
#define DV    128
#define TOT   3088      // 1024+512+512+1024+8+8
#define CONVD 2048
#define KSZ   4
#define BT    (BB*TT)   // 2048
#define CHUNK 64
#define NCHUNK (TT/CHUNK)   // 16
#define NBH   (BB*NQ)       // 16
#define NPAD1 3200          // 3088 padded to 25*128
#define JW    32            // phaseB column-group width

typedef __attribute__((ext_vector_type(8))) short short8v;
typedef __attribute__((ext_vector_type(4))) float f32x4;
typedef unsigned short ushort_t;
typedef unsigned int uint_t;

__device__ __forceinline__ float siluf(float x)     { return x / (1.f + expf(-x)); }
__device__ __forceinline__ float sigmoidf_(float x) { return 1.f / (1.f + expf(-x)); }
__device__ __forceinline__ float softplusf_(float x){ return x > 15.f ? x : log1pf(expf(x)); }

__device__ __forceinline__ ushort_t f2bf(float f) {
    uint_t u = __builtin_bit_cast(uint_t, f);
    u = (u + 0x7fff + ((u >> 16) & 1)) >> 16;
    return (ushort_t)u;
}
__device__ __forceinline__ float bf2f(ushort_t u) {
    uint_t v = ((uint_t)u) << 16;
    return __builtin_bit_cast(float, v);
}
__device__ __forceinline__ ushort4 pack4(f32x4 v) {
    ushort4 p; p.x = f2bf(v[0]); p.y = f2bf(v[1]); p.z = f2bf(v[2]); p.w = f2bf(v[3]);
    return p;
}

// ---------------- elementwise f32 -> bf16 ----------------
__global__ __launch_bounds__(256) void f2bf_kernel(const float* __restrict__ src,
                                                   ushort_t* __restrict__ dst) {
    int i = (blockIdx.x * 256 + threadIdx.x) * 4;
    float4 v = *(const float4*)(src + i);
    ushort4 o;
    o.x = f2bf(v.x); o.y = f2bf(v.y); o.z = f2bf(v.z); o.w = f2bf(v.w);
    *(ushort4*)(dst + i) = o;
}

// ---------------- tiled transpose + convert: dst[n][k] = bf16(src[k][n]) ----------------
__global__ __launch_bounds__(256) void transpose_f2bf(const float* __restrict__ src,
                                                      ushort_t* __restrict__ dst,
                                                      int K, int N) {
    __shared__ float tile[32][33];
    int n0 = blockIdx.x * 32, k0 = blockIdx.y * 32;
    int c = threadIdx.x & 31, rbase = threadIdx.x >> 5;
    #pragma unroll
    for (int i = 0; i < 4; i++) {
        int r = rbase + i * 8;
        int n = n0 + c;
        tile[r][c] = (n < N) ? src[(size_t)(k0 + r) * N + n] : 0.f;
    }
    __syncthreads();
    #pragma unroll
    for (int i = 0; i < 4; i++) {
        int r = rbase + i * 8;
        dst[(size_t)(n0 + r) * K + k0 + c] = f2bf(tile[c][r]);
    }
}

// ---------------- bf16 MFMA GEMM (m97 structure): C[M,N] = A[M,K] @ BT[N,K]^T ----------------
__global__ __launch_bounds__(256) void gemm_bf16(const ushort_t* __restrict__ A,
                                                 const ushort_t* __restrict__ BTm,
                                                 float* __restrict__ C,
                                                 int K, int Nc, int ldc) {
    __shared__ ushort_t As[128 * 32];
    __shared__ ushort_t Bs[128 * 32];
    int tid = threadIdx.x;
    int wave = tid >> 6, lane = tid & 63;
    int wr = wave >> 1, wc = wave & 1;
    int row0 = blockIdx.y * 128, col0 = blockIdx.x * 128;

    f32x4 zero4 = {0.f, 0.f, 0.f, 0.f};
    f32x4 acc[4][4];
    #pragma unroll
    for (int m = 0; m < 4; m++)
        #pragma unroll
        for (int n = 0; n < 4; n++) acc[m][n] = zero4;

    int srow = wave * 32 + (lane >> 2);
    int koff = (lane & 3) * 8;
    const ushort_t* gA0 = A + (size_t)(row0 + srow) * K + koff;
    const ushort_t* gA1 = A + (size_t)(row0 + srow + 16) * K + koff;
    const ushort_t* gB0 = BTm + (size_t)(col0 + srow) * K + koff;
    const ushort_t* gB1 = BTm + (size_t)(col0 + srow + 16) * K + koff;
    ushort_t* lA0 = As + (wave * 2 + 0) * 512;
    ushort_t* lA1 = As + (wave * 2 + 1) * 512;
    ushort_t* lB0 = Bs + (wave * 2 + 0) * 512;
    ushort_t* lB1 = Bs + (wave * 2 + 1) * 512;

    for (int k0 = 0; k0 < K; k0 += 32) {
        __builtin_amdgcn_global_load_lds(
            (const __attribute__((address_space(1))) void*)(gA0 + k0),
            (__attribute__((address_space(3))) void*)lA0, 16, 0, 0);
        __builtin_amdgcn_global_load_lds(
            (const __attribute__((address_space(1))) void*)(gA1 + k0),
            (__attribute__((address_space(3))) void*)lA1, 16, 0, 0);
        __builtin_amdgcn_global_load_lds(
            (const __attribute__((address_space(1))) void*)(gB0 + k0),
            (__attribute__((address_space(3))) void*)lB0, 16, 0, 0);
        __builtin_amdgcn_global_load_lds(
            (const __attribute__((address_space(1))) void*)(gB1 + k0),
            (__attribute__((address_space(3))) void*)lB1, 16, 0, 0);
        __syncthreads();

        short8v af[4], bf[4];
        #pragma unroll
        for (int m = 0; m < 4; m++)
            af[m] = *(const short8v*)(As + (wr * 64 + m * 16 + (lane & 15)) * 32 + (lane >> 4) * 8);
        #pragma unroll
        for (int n = 0; n < 4; n++)
            bf[n] = *(const short8v*)(Bs + (wc * 64 + n * 16 + (lane & 15)) * 32 + (lane >> 4) * 8);
        #pragma unroll
        for (int m = 0; m < 4; m++)
            #pragma unroll
            for (int n = 0; n < 4; n++)
                acc[m][n] = __builtin_amdgcn_mfma_f32_16x16x32_bf16(af[m], bf[n], acc[m][n], 0, 0, 0);
        __syncthreads();
    }

    #pragma unroll
    for (int m = 0; m < 4; m++) {
        #pragma unroll
        for (int n = 0; n < 4; n++) {
            int row = row0 + wr * 64 + m * 16 + (lane >> 4) * 4;
            int col = col0 + wc * 64 + n * 16 + (lane & 15);
            if (col < Nc) {
                #pragma unroll
                for (int e = 0; e < 4; e++)
                    C[(size_t)(row + e) * ldc + col] = acc[m][n][e];
            }
        }
    }
}

// ---------------- conv + silu + split + l2norm + beta/g ----------------
// outputs: qb (bf16), kb (bf16), kn (f32), vn (f32), beta, g
__global__ __launch_bounds__(256) void conv_split_kernel(const float* __restrict__ mixed,
                                                         const float* __restrict__ conv_w,
                                                         const float* __restrict__ A_log,
                                                         const float* __restrict__ dt_bias,
                                                         ushort_t* __restrict__ qb,
                                                         ushort_t* __restrict__ kb,
                                                         float* __restrict__ kn,
                                                         float* __restrict__ vn,
                                                         float* __restrict__ beta,
                                                         float* __restrict__ g) {
    int bt = blockIdx.x;
    int t = bt & (TT - 1);
    int tid = threadIdx.x;
    int c0 = tid * 8;

    float val[8];
    #pragma unroll
    for (int i = 0; i < 8; i++) val[i] = 0.f;
    #pragma unroll
    for (int j = 0; j < KSZ; j++) {
        int tt = t - (KSZ - 1) + j;
        if (tt >= 0) {
            const float* src = mixed + (size_t)(bt - (KSZ - 1) + j) * TOT + c0;
            #pragma unroll
            for (int i = 0; i < 8; i++) val[i] += src[i] * conv_w[(c0 + i) * KSZ + j];
        }
    }
    #pragma unroll
    for (int i = 0; i < 8; i++) val[i] = siluf(val[i]);

    float ss = 0.f;
    #pragma unroll
    for (int i = 0; i < 8; i++) ss += val[i] * val[i];
    #pragma unroll
    for (int m = 1; m < 16; m <<= 1) ss += __shfl_xor(ss, m, 64);
    float rs = rsqrtf(ss + 1e-6f);

    if (tid < 128) {                      // q -> l2norm * DK^-0.5, bf16 only
        float sc = rs * 0.08838834764831845f;
        short8v pk;
        #pragma unroll
        for (int i = 0; i < 8; i++) pk[i] = (short)f2bf(val[i] * sc);
        *(short8v*)(qb + (size_t)bt * 1024 + c0) = pk;
    } else if (tid < 192) {               // k -> l2norm, f32 + bf16
        int o = c0 - 1024;
        short8v pk;
        #pragma unroll
        for (int i = 0; i < 8; i++) {
            float kv = val[i] * rs;
            kn[(size_t)bt * 512 + o + i] = kv;
            pk[i] = (short)f2bf(kv);
        }
        *(short8v*)(kb + (size_t)bt * 512 + o) = pk;
    } else {                              // v -> silu only, f32
        #pragma unroll
        for (int i = 0; i < 8; i++) vn[(size_t)bt * 512 + (c0 - 1536) + i] = val[i];
    }
    if (tid < 8) {
        beta[bt * 8 + tid] = sigmoidf_(mixed[(size_t)bt * TOT + 3072 + tid]);
    } else if (tid < 16) {
        int h = tid - 8;
        g[bt * 8 + h] = -expf(A_log[h]) * softplusf_(mixed[(size_t)bt * TOT + 3080 + h] + dt_bias[h]);
    }
}

// ---------------- Phase A: per-chunk UT transform (MFMA M, register substitution) ----------------
// W = T^-1 diag(beta) V (fp32); Znegb = -T^-1 diag(beta*Gamma) K (bf16); knT bf16 transposed k.
__global__ __launch_bounds__(256) void phaseA_kernel(const float* __restrict__ kn,
                                                     const float* __restrict__ vn,
                                                     const float* __restrict__ beta,
                                                     const float* __restrict__ g,
                                                     float* __restrict__ W,
                                                     ushort_t* __restrict__ Znegb,
                                                     ushort_t* __restrict__ knT,
                                                     float* __restrict__ Bvec) {
    int chunk = blockIdx.x;
    int bh = chunk >> 4, c = chunk & 15;
    int b = bh >> 3, h = bh & 7, hk = h >> 1;
    int bt0 = b * TT + c * CHUNK;
    int tid = threadIdx.x;
    int wave = tid >> 6, lane = tid & 63;
    int lr = lane & 15, lg = lane >> 4;

    __shared__ __align__(16) ushort_t kcb[64 * 128];  // bf16 k, XOR-swizzled rows
    __shared__ float Ms[64][65];
    __shared__ float Bv[64], Bev[64], bev[64];

    if (tid < 64) {   // wave 0: cumulative log-decay scan
        float v = g[(size_t)(bt0 + tid) * 8 + h];
        #pragma unroll
        for (int off = 1; off < 64; off <<= 1) {
            float n = __shfl_up(v, off, 64);
            if (tid >= off) v += n;
        }
        Bv[tid] = v;
        Bev[tid] = expf(v);
        bev[tid] = beta[(size_t)(bt0 + tid) * 8 + h];
        Bvec[chunk * 64 + tid] = v;
    }
    // stage k as bf16, swizzled: byte (r*256 + k*2) ^ ((r&7)<<4)
    for (int i = tid; i < 1024; i += 256) {
        int r = i >> 4, k16 = i & 15;
        const float* src = kn + (size_t)(bt0 + r) * 512 + hk * 128 + k16 * 8;
        float4 v0 = *(const float4*)src;
        float4 v1 = *(const float4*)(src + 4);
        short8v pk;
        pk[0] = (short)f2bf(v0.x); pk[1] = (short)f2bf(v0.y);
        pk[2] = (short)f2bf(v0.z); pk[3] = (short)f2bf(v0.w);
        pk[4] = (short)f2bf(v1.x); pk[5] = (short)f2bf(v1.y);
        pk[6] = (short)f2bf(v1.z); pk[7] = (short)f2bf(v1.w);
        int a = (r * 256 + k16 * 16) ^ ((r & 7) << 4);
        *(short8v*)((char*)kcb + a) = pk;
    }
    __syncthreads();

    // M via MFMA: wave w -> rows [16w,16w+16), s-bands 0..w
    {
        int t_lane = wave * 16 + lr;
        short8v af[4];
        #pragma unroll
        for (int ks = 0; ks < 4; ks++) {
            int a = (t_lane * 256 + ks * 64 + lg * 16) ^ ((t_lane & 7) << 4);
            af[ks] = *(const short8v*)((const char*)kcb + a);
        }
        for (int sb = 0; sb <= wave; sb++) {
            f32x4 macc = {0.f, 0.f, 0.f, 0.f};
            int s_lane = sb * 16 + lr;
            #pragma unroll
            for (int ks = 0; ks < 4; ks++) {
                int a = (s_lane * 256 + ks * 64 + lg * 16) ^ ((s_lane & 7) << 4);
                short8v bfr = *(const short8v*)((const char*)kcb + a);
                macc = __builtin_amdgcn_mfma_f32_16x16x32_bf16(af[ks], bfr, macc, 0, 0, 0);
            }
            #pragma unroll
            for (int e = 0; e < 4; e++) {
                int trow = wave * 16 + lg * 4 + e;
                int scol = sb * 16 + lr;
                Ms[trow][scol] = (scol < trow) ? macc[e] * bev[trow] * expf(Bv[trow] - Bv[scol]) : 0.f;
            }
        }
    }

    // X init in registers: col tid<128 -> beta*v ; col tid>=128 -> beta*Gamma*k
    float Xr[64];
    if (tid < 128) {
        #pragma unroll
        for (int t = 0; t < 64; t++)
            Xr[t] = bev[t] * vn[(size_t)(bt0 + t) * 512 + hk * 128 + tid];
    } else {
        int r = tid - 128;
        #pragma unroll
        for (int t = 0; t < 64; t++)
            Xr[t] = bev[t] * Bev[t] * kn[(size_t)(bt0 + t) * 512 + hk * 128 + r];
    }
    __syncthreads();   // Ms ready

    // forward substitution, column-private, zero barriers, static indexing
    #pragma unroll
    for (int t = 1; t < 64; t++) {
        float a0 = 0.f, a1 = 0.f, a2 = 0.f, a3 = 0.f;
        #pragma unroll
        for (int s = 0; s + 4 <= t; s += 4) {
            a0 += Ms[t][s] * Xr[s];     a1 += Ms[t][s + 1] * Xr[s + 1];
            a2 += Ms[t][s + 2] * Xr[s + 2]; a3 += Ms[t][s + 3] * Xr[s + 3];
        }
        #pragma unroll
        for (int s = t & ~3; s < t; s++) a0 += Ms[t][s] * Xr[s];
        Xr[t] -= (a0 + a1) + (a2 + a3);
    }

    if (tid < 128) {
        float* Wc = W + (size_t)chunk * 8192 + tid;
        #pragma unroll
        for (int t = 0; t < 64; t++) Wc[t * 128] = Xr[t];
    } else {
        ushort_t* Zc = Znegb + (size_t)chunk * 8192 + (tid - 128);
        #pragma unroll
        for (int t = 0; t < 64; t++) Zc[t * 128] = f2bf(-Xr[t]);
    }

    // transposed bf16 k for phaseB (one writer per kv-head pair)
    if ((h & 1) == 0) {
        ushort_t* kT = knT + (size_t)(b * 4 + hk) * 131072 + c * 64;
        for (int i = tid; i < 8192; i += 256) {
            int r = i >> 6, tt = i & 63;
            int a = (tt * 256 + r * 2) ^ ((tt & 7) << 4);
            kT[(size_t)r * 1024 + tt] = *(const ushort_t*)((const char*)kcb + a);
        }
    }
}

// ---------------- Phase B (MFMA, software-pipelined): sequential over chunks ----------------
// All global operands (Z, W, kT, Bvec) for chunk c+1 are prefetched into registers while
// chunk c computes: the only things left on the per-chunk critical path are the two
// barriers, 16 MFMAs, and the bf16 pack VALU.
__device__ __forceinline__ int swzSt(int j, int k) {   // St[j][k]: 32x128 bf16
    int a = j * 256 + k * 2;
    return a ^ ((j & 7) << 4);
}
__device__ __forceinline__ int swzUt(int j, int s) {   // Ut[j][s]: 32x64 bf16
    int a = j * 128 + s * 2;
    return a ^ ((j & 7) << 4);
}

__global__ __launch_bounds__(256) void phaseB_mfma(const ushort_t* __restrict__ knT,
                                                   const ushort_t* __restrict__ Znegb,
                                                   const float* __restrict__ W,
                                                   const float* __restrict__ Bvec,
                                                   ushort_t* __restrict__ SallT,
                                                   ushort_t* __restrict__ UTg) {
    int bh = blockIdx.x >> 2, cg = blockIdx.x & 3;
    int b = bh >> 3, h = bh & 7, hk = h >> 1;
    int j0 = cg * JW;
    int tid = threadIdx.x;
    int wave = tid >> 6, lane = tid & 63;
    int lr = lane & 15, lg = lane >> 4;
    int t0 = wave * 16;

    __shared__ __align__(16) ushort_t St[JW * 128];
    __shared__ __align__(16) ushort_t Ut[JW * 64];

    for (int i = tid * 8; i < JW * 128; i += 2048)
        *(int4*)(St + i) = make_int4(0, 0, 0, 0);

    f32x4 Sacc[2][2];
    #pragma unroll
    for (int fr = 0; fr < 2; fr++)
        #pragma unroll
        for (int fc = 0; fc < 2; fc++) Sacc[fr][fc] = (f32x4){0.f, 0.f, 0.f, 0.f};

    const ushort_t* kTbase = knT + (size_t)(b * 4 + hk) * 131072;
    int chunk0 = bh * 16;

    // ---- prologue: prefetch chunk 0 operands into registers
    short8v za[4], ka[4];
    f32x4 wv[2];
    f32x4 bvv[4];
    float b63;
    {
        const ushort_t* Zc = Znegb + (size_t)chunk0 * 8192;
        #pragma unroll
        for (int ks = 0; ks < 4; ks++)
            za[ks] = *(const short8v*)(Zc + (size_t)(t0 + lr) * 128 + ks * 32 + lg * 8);
        const float* Wc = W + (size_t)chunk0 * 8192 + j0;
        #pragma unroll
        for (int fc = 0; fc < 2; fc++)
            #pragma unroll
            for (int e = 0; e < 4; e++)
                wv[fc][e] = Wc[(size_t)(t0 + lg * 4 + e) * 128 + fc * 16 + lr];
        #pragma unroll
        for (int fr = 0; fr < 2; fr++)
            #pragma unroll
            for (int ss = 0; ss < 2; ss++)
                ka[fr * 2 + ss] = *(const short8v*)(kTbase +
                    (size_t)(wave * 32 + fr * 16 + lr) * 1024 + ss * 32 + lg * 8);
        #pragma unroll
        for (int q = 0; q < 4; q++)
            bvv[q] = *(const f32x4*)(Bvec + chunk0 * 64 + (q >> 1) * 32 + lg * 8 + (q & 1) * 4);
        b63 = Bvec[chunk0 * 64 + 63];
    }

    for (int c = 0; c < NCHUNK; c++) {
        int chunk = chunk0 + c;
        // store S_c (chunk-start state) as bf16 transposed [j][r]
        ushort_t* SgT = SallT + (size_t)chunk * 16384;
        #pragma unroll
        for (int fr = 0; fr < 2; fr++)
            #pragma unroll
            for (int fc = 0; fc < 2; fc++) {
                int r0 = wave * 32 + fr * 16 + lg * 4;
                int j = j0 + fc * 16 + lr;
                *(ushort4*)(SgT + (size_t)j * 128 + r0) = pack4(Sacc[fr][fc]);
            }
        // C-input of product 1 from prefetched W
        f32x4 Uacc[2];
        Uacc[0] = wv[0];
        Uacc[1] = wv[1];

        __syncthreads();   // B1: St (prev chunk) visible

        // ---- product 1: U = W + (-Z) * S   (za, Uacc prefetched; St from LDS)
        #pragma unroll
        for (int ks = 0; ks < 4; ks++)
            #pragma unroll
            for (int fc = 0; fc < 2; fc++) {
                short8v sb = *(const short8v*)((const char*)St + swzSt(fc * 16 + lr, ks * 32 + lg * 8));
                Uacc[fc] = __builtin_amdgcn_mfma_f32_16x16x32_bf16(za[ks], sb, Uacc[fc], 0, 0, 0);
            }
        // write U: global bf16 transposed [j][t] + LDS transposed bf16
        ushort_t* UTc = UTg + (size_t)chunk * 8192;
        #pragma unroll
        for (int fc = 0; fc < 2; fc++) {
            int jl = fc * 16 + lr;
            ushort4 pu = pack4(Uacc[fc]);
            *(ushort4*)(UTc + (size_t)(j0 + jl) * 64 + t0 + lg * 4) = pu;
            *(ushort4*)((char*)Ut + swzUt(jl, t0 + lg * 4)) = pu;
        }
        // prefetch Z/W for chunk c+1 (za/wv fully consumed above)
        if (c + 1 < NCHUNK) {
            const ushort_t* Zn = Znegb + (size_t)(chunk + 1) * 8192;
            #pragma unroll
            for (int ks = 0; ks < 4; ks++)
                za[ks] = *(const short8v*)(Zn + (size_t)(t0 + lr) * 128 + ks * 32 + lg * 8);
            const float* Wn = W + (size_t)(chunk + 1) * 8192 + j0;
            #pragma unroll
            for (int fc = 0; fc < 2; fc++)
                #pragma unroll
                for (int e = 0; e < 4; e++)
                    wv[fc][e] = Wn[(size_t)(t0 + lg * 4 + e) * 128 + fc * 16 + lr];
        }
        // gamma-scale state
        float gC = expf(b63);
        #pragma unroll
        for (int fr = 0; fr < 2; fr++)
            #pragma unroll
            for (int fc = 0; fc < 2; fc++)
                #pragma unroll
                for (int e = 0; e < 4; e++) Sacc[fr][fc][e] *= gC;

        __syncthreads();   // B2: Ut ready

        // per-lane decay factors from prefetched Bvec (no LDS, no wave0 special-case)
        float eb[2][8];
        #pragma unroll
        for (int ss = 0; ss < 2; ss++)
            #pragma unroll
            for (int e = 0; e < 8; e++)
                eb[ss][e] = expf(b63 - bvv[ss * 2 + (e >> 2)][e & 3]);

        // ---- product 2: S += K_hat^T * U
        #pragma unroll
        for (int fr = 0; fr < 2; fr++) {
            #pragma unroll
            for (int ss = 0; ss < 2; ss++) {
                short8v a;
                #pragma unroll
                for (int e = 0; e < 8; e++)
                    a[e] = (short)f2bf(bf2f((ushort_t)ka[fr * 2 + ss][e]) * eb[ss][e]);
                #pragma unroll
                for (int fc = 0; fc < 2; fc++) {
                    short8v ub = *(const short8v*)((const char*)Ut + swzUt(fc * 16 + lr, ss * 32 + lg * 8));
                    Sacc[fr][fc] = __builtin_amdgcn_mfma_f32_16x16x32_bf16(a, ub, Sacc[fr][fc], 0, 0, 0);
                }
            }
        }
        // prefetch kT/Bvec for chunk c+1 (ka/bvv/b63 fully consumed above)
        if (c + 1 < NCHUNK) {
            #pragma unroll
            for (int fr = 0; fr < 2; fr++)
                #pragma unroll
                for (int ss = 0; ss < 2; ss++)
                    ka[fr * 2 + ss] = *(const short8v*)(kTbase +
                        (size_t)(wave * 32 + fr * 16 + lr) * 1024 + (c + 1) * 64 + ss * 32 + lg * 8);
            #pragma unroll
            for (int q = 0; q < 4; q++)
                bvv[q] = *(const f32x4*)(Bvec + (chunk + 1) * 64 + (q >> 1) * 32 + lg * 8 + (q & 1) * 4);
            b63 = Bvec[(chunk + 1) * 64 + 63];
        }
        // write S^T bf16 for next chunk's product 1
        #pragma unroll
        for (int fr = 0; fr < 2; fr++)
            #pragma unroll
            for (int fc = 0; fc < 2; fc++) {
                int r = wave * 32 + fr * 16 + lg * 4;
                int j = fc * 16 + lr;
                *(ushort4*)((char*)St + swzSt(j, r)) = pack4(Sacc[fr][fc]);
            }
    }
}

// ---------------- Phase C (MFMA): O = Gamma*(Q S) + P~ U ----------------
__global__ __launch_bounds__(256) void phaseC_mfma(const ushort_t* __restrict__ qb,
                                                   const ushort_t* __restrict__ kb,
                                                   const ushort_t* __restrict__ UTg,
                                                   const ushort_t* __restrict__ SallT,
                                                   const float* __restrict__ Bvec,
                                                   float* __restrict__ o) {
    int chunk = blockIdx.x;
    int bh = chunk >> 4, c = chunk & 15;
    int b = bh >> 3, h = bh & 7, hk = h >> 1;
    int bt0 = b * TT + c * CHUNK;
    int tid = threadIdx.x, wave = tid >> 6, lane = tid & 63;
    int lr = lane & 15, lg = lane >> 4;

    __shared__ float Bv[64], Bev[64];
    __shared__ __align__(16) ushort_t Pb[64 * 64];   // P~ bf16, swizzled

    if (tid < 64) { float v = Bvec[chunk * 64 + tid]; Bv[tid] = v; Bev[tid] = expf(v); }
    __syncthreads();

    int t_lane = wave * 16 + lr;
    const ushort_t* qrow = qb + (size_t)(bt0 + t_lane) * 1024 + h * 128;
    short8v qa[4];
    #pragma unroll
    for (int ks = 0; ks < 4; ks++) qa[ks] = *(const short8v*)(qrow + ks * 32 + lg * 8);

    // ---- P = mask(exp(Bt-Bs) * Q K^T): wave w -> rows [16w,16w+16), all 4 s-bands
    #pragma unroll
    for (int sb = 0; sb < 4; sb++) {
        f32x4 pacc = {0.f, 0.f, 0.f, 0.f};
        const ushort_t* krow = kb + (size_t)(bt0 + sb * 16 + lr) * 512 + hk * 128;
        #pragma unroll
        for (int ks = 0; ks < 4; ks++) {
            short8v kf = *(const short8v*)(krow + ks * 32 + lg * 8);
            pacc = __builtin_amdgcn_mfma_f32_16x16x32_bf16(qa[ks], kf, pacc, 0, 0, 0);
        }
        int scol = sb * 16 + lr;
        #pragma unroll
        for (int e = 0; e < 4; e++) {
            int trow = wave * 16 + lg * 4 + e;
            float val = (scol <= trow) ? pacc[e] * expf(Bv[trow] - Bv[scol]) : 0.f;
            int a = (trow * 128 + scol * 2) ^ ((trow & 7) << 4);
            *(ushort_t*)((char*)Pb + a) = f2bf(val);
        }
    }

    // ---- QS: acc[n] = Q @ S (B-frags straight from global SallT), then scale by Gamma
    float Ge[4];
    #pragma unroll
    for (int e = 0; e < 4; e++) Ge[e] = Bev[wave * 16 + lg * 4 + e];
    const ushort_t* ST = SallT + (size_t)chunk * 16384;
    f32x4 acc[8];
    #pragma unroll
    for (int n = 0; n < 8; n++) {
        acc[n] = (f32x4){0.f, 0.f, 0.f, 0.f};
        int j = n * 16 + lr;
        #pragma unroll
        for (int rs = 0; rs < 4; rs++) {
            short8v sf = *(const short8v*)(ST + (size_t)j * 128 + rs * 32 + lg * 8);
            acc[n] = __builtin_amdgcn_mfma_f32_16x16x32_bf16(qa[rs], sf, acc[n], 0, 0, 0);
        }
        #pragma unroll
        for (int e = 0; e < 4; e++) acc[n][e] *= Ge[e];
    }
    __syncthreads();   // Pb ready

    // ---- acc += P~ @ U (A-frags from Pb LDS, B-frags from global UT)
    short8v pa[2];
    #pragma unroll
    for (int ks = 0; ks < 2; ks++) {
        int a = (t_lane * 128 + (ks * 32 + lg * 8) * 2) ^ ((t_lane & 7) << 4);
        pa[ks] = *(const short8v*)((const char*)Pb + a);
    }
    const ushort_t* UTc = UTg + (size_t)chunk * 8192;
    #pragma unroll
    for (int n = 0; n < 8; n++) {
        int j = n * 16 + lr;
        #pragma unroll
        for (int ks = 0; ks < 2; ks++) {
            short8v uf = *(const short8v*)(UTc + (size_t)j * 64 + ks * 32 + lg * 8);
            acc[n] = __builtin_amdgcn_mfma_f32_16x16x32_bf16(pa[ks], uf, acc[n], 0, 0, 0);
        }
    }
    #pragma unroll
    for (int n = 0; n < 8; n++) {
        int j = n * 16 + lr;
        #pragma unroll
        for (int e = 0; e < 4; e++) {
            int t = wave * 16 + lg * 4 + e;
            o[(size_t)(bt0 + t) * 1024 + h * 128 + j] = acc[n][e];
        }
    }
}

// ---------------- gated RMS norm + silu(z) gate -> bf16 ----------------
__global__ __launch_bounds__(64) void norm_gate_kernel(const float* __restrict__ o_scan,
                                                       const float* __restrict__ mixed,
                                                       const float* __restrict__ norm_w,
                                                       ushort_t* __restrict__ ginb) {
    int bth = blockIdx.x;
    int bt = bth >> 3, h = bth & 7;
    int lane = threadIdx.x;
    size_t base = (size_t)bt * 1024 + h * 128;
    float o0 = o_scan[base + lane];
    float o1 = o_scan[base + lane + 64];
    float ss = o0 * o0 + o1 * o1;
    #pragma unroll
    for (int m = 1; m < 64; m <<= 1) ss += __shfl_xor(ss, m, 64);
    float r = rsqrtf(ss * (1.f / 128.f) + 1e-5f);
    size_t zbase = (size_t)bt * TOT + 2048 + h * 128;
    float z0 = mixed[zbase + lane];
    float z1 = mixed[zbase + lane + 64];
    ginb[base + lane]      = f2bf(o0 * r * norm_w[lane]      * siluf(z0));
    ginb[base + lane + 64] = f2bf(o1 * r * norm_w[lane + 64] * siluf(z1));
}

extern "C" void kernel_launch(void* const* d_in, const int* in_sizes, int n_in,
                              void* d_out, int out_size, void* d_ws, size_t ws_size,
                              hipStream_t stream) {
    const float* x       = (const float*)d_in[0];
    const float* w_in    = (const float*)d_in[1];
    const float* conv_w  = (const float*)d_in[2];
    const float* A_log   = (const float*)d_in[3];
    const float* dt_bias = (const float*)d_in[4];
    const float* norm_w  = (const float*)d_in[5];
    const float* w_out   = (const float*)d_in[6];
    float* out = (float*)d_out;

    // Workspace map (units: FLOATS; bf16 buffers take elem_count/2 floats!)
    float* ws = (float*)d_ws;
    float* mixed = ws;                              // 6,324,224 f   [2048][3088] f32
    float* kn    = mixed + (size_t)BT * TOT;        // 1,048,576 f   [2048][512] f32
    float* vn    = kn + (size_t)BT * 512;           // 1,048,576 f   [2048][512] f32
    float* beta  = vn + (size_t)BT * 512;           // 16,384 f
    float* gdec  = beta + BT * 8;                   // 16,384 f
    float* Wu    = gdec + BT * 8;                   // 2,097,152 f   W [256][64][128] f32; oscan alias
    float* Bvec  = Wu + (size_t)BT * 1024;          // 16,384 f
    float* qbf   = Bvec + NBH * NCHUNK * 64;        // 1,048,576 f   qb: 2048*1024 bf16 = 2,097,152 us
    float* kbf   = qbf + 1048576;                   // 524,288 f     kb: 2048*512 bf16 = 1,048,576 us
    float* knTf  = kbf + 524288;                    // 524,288 f     knT: 8*128*1024 us  ┐
    float* Znf   = knTf + 524288;                   // 1,048,576 f   Zneg: 256*8192 us   │ bt1 spans these
    float* UTf   = Znf + 1048576;                   // 1,048,576 f   UT: 256*8192 us     ┘ (+64K f of UTf)
    float* SallTf= UTf + 1048576;                   // 2,097,152 f   SallT: 256*16384 us; xb alias
    float* bt2f  = SallTf + 2097152;                // 524,288 f     w_out^T: 1024*1024 us
    // total: 17,383,424 f = 69.5 MB

    ushort_t* qb    = (ushort_t*)qbf;
    ushort_t* kb    = (ushort_t*)kbf;
    ushort_t* knTb  = (ushort_t*)knTf;
    ushort_t* Znegb = (ushort_t*)Znf;
    ushort_t* UTb   = (ushort_t*)UTf;
    ushort_t* SallT = (ushort_t*)SallTf;
    ushort_t* bt2   = (ushort_t*)bt2f;
    // liveness-disjoint aliases:
    ushort_t* xb    = (ushort_t*)SallTf;            // x bf16 (1,048,576 f): dead before phaseB writes SallT
    ushort_t* bt1   = (ushort_t*)knTf;              // w_in^T bf16 (1,638,400 f): dead after GEMM1,
                                                    //   before phaseA writes knT/Zneg & phaseB writes UT
    ushort_t* ginb  = (ushort_t*)qbf;               // GEMM2 input (1,048,576 f): qb dead after phaseC
    float* oscan    = Wu;                           // phaseC out: W dead after phaseB

    // 0) converts
    f2bf_kernel<<<(BT * HID) / 1024, 256, 0, stream>>>(x, xb);
    transpose_f2bf<<<dim3(NPAD1 / 32, HID / 32), 256, 0, stream>>>(w_in, bt1, HID, TOT);
    transpose_f2bf<<<dim3(HID / 32, HID / 32), 256, 0, stream>>>(w_out, bt2, HID, HID);

    // 1) mixed = x @ w_in  (bf16 MFMA)
    gemm_bf16<<<dim3(NPAD1 / 128, BT / 128), 256, 0, stream>>>(xb, bt1, mixed, HID, TOT, TOT);

    // 2) conv + silu + split + l2norm + beta/g
    conv_split_kernel<<<BT, 256, 0, stream>>>(mixed, conv_w, A_log, dt_bias, qb, kb, kn, vn, beta, gdec);

    // 3) chunkwise delta-rule scan
    phaseA_kernel<<<NBH * NCHUNK, 256, 0, stream>>>(kn, vn, beta, gdec, Wu, Znegb, knTb, Bvec);
    phaseB_mfma<<<NBH * 4, 256, 0, stream>>>(knTb, Znegb, Wu, Bvec, SallT, UTb);
    phaseC_mfma<<<NBH * NCHUNK, 256, 0, stream>>>(qb, kb, UTb, SallT, Bvec, oscan);

    // 4) gated RMS norm + silu(z) -> bf16
    norm_gate_kernel<<<BT * NQ, 64, 0, stream>>>(oscan, mixed, norm_w, ginb);

    // 5) out = gin @ w_out  (bf16 MFMA)
    gemm_bf16<<<dim3(HID / 128, BT / 128), 256, 0, stream>>>(ginb, bt2, out, HID, HID, HID);
}